// Round 4
// baseline (699.695 us; speedup 1.0000x reference)
//
#include <hip/hip_runtime.h>

#define NN 50000
#define NE 800000
#define DIM 128
#define NLAYERS 3

// ---------------- CSR build ----------------
__global__ void hist_kernel(const int* __restrict__ tgt, int* __restrict__ counts, int E) {
    int e = blockIdx.x * blockDim.x + threadIdx.x;
    if (e < E) atomicAdd(&counts[tgt[e]], 1);
}

__global__ __launch_bounds__(256) void scan_partial_kernel(const int* __restrict__ counts,
                                                           int* __restrict__ psum, int n) {
    __shared__ int ws[4];
    int b = blockIdx.x, t = threadIdx.x;
    int idx = b * 1024 + t * 4;
    int v = 0;
    if (idx < n) {
        int4 c = *(const int4*)(counts + idx);
        v = c.x + c.y + c.z + c.w;
    }
#pragma unroll
    for (int o = 32; o > 0; o >>= 1) v += __shfl_xor(v, o);
    int lane = t & 63, wid = t >> 6;
    if (lane == 0) ws[wid] = v;
    __syncthreads();
    if (t == 0) psum[b] = ws[0] + ws[1] + ws[2] + ws[3];
}

__global__ __launch_bounds__(64) void scan_small_kernel(const int* __restrict__ psum,
                                                        int* __restrict__ pbase,
                                                        int* __restrict__ offsets,
                                                        int nb, int n) {
    int lane = threadIdx.x;
    int v = (lane < nb) ? psum[lane] : 0;
    int incl = v;
#pragma unroll
    for (int o = 1; o < 64; o <<= 1) {
        int t = __shfl_up(incl, o);
        if (lane >= o) incl += t;
    }
    if (lane < nb) pbase[lane] = incl - v;
    if (lane == 63) offsets[n] = incl;
}

__global__ __launch_bounds__(256) void scan_apply_kernel(const int* __restrict__ counts,
                                                         const int* __restrict__ pbase,
                                                         int* __restrict__ offsets,
                                                         int* __restrict__ cursor, int n) {
    __shared__ int ws[4];
    int b = blockIdx.x, t = threadIdx.x;
    int lane = t & 63, wid = t >> 6;
    int idx = b * 1024 + t * 4;
    int4 c = make_int4(0, 0, 0, 0);
    if (idx < n) c = *(const int4*)(counts + idx);
    int tsum = c.x + c.y + c.z + c.w;
    int incl = tsum;
#pragma unroll
    for (int o = 1; o < 64; o <<= 1) {
        int tt = __shfl_up(incl, o);
        if (lane >= o) incl += tt;
    }
    if (lane == 63) ws[wid] = incl;
    __syncthreads();
    int wbase = pbase[b];
    for (int w = 0; w < wid; w++) wbase += ws[w];
    if (idx < n) {
        int e0 = wbase + incl - tsum;
        int4 o;
        o.x = e0;
        o.y = e0 + c.x;
        o.z = o.y + c.y;
        o.w = o.z + c.z;
        *(int4*)(offsets + idx) = o;
        *(int4*)(cursor + idx) = o;
    }
}

__global__ void scatter_kernel(const int* __restrict__ src, const int* __restrict__ tgt,
                               const float* __restrict__ ea,
                               int* __restrict__ cursor, int2* __restrict__ sedge, int E) {
    int e = blockIdx.x * blockDim.x + threadIdx.x;
    if (e >= E) return;
    int t = tgt[e];
    int pos = atomicAdd(&cursor[t], 1);
    sedge[pos] = make_int2(src[e], __float_as_int(ea[e]));
}

// ---------------- per-layer aggregation ----------------
__global__ __launch_bounds__(128) void agg_kernel(
    const float* __restrict__ hprev, const int* __restrict__ offs,
    const int2* __restrict__ sedge,
    const float* __restrict__ lw, const float* __restrict__ lb,
    const float* __restrict__ epsp, int layer,
    float* __restrict__ outb, int N) {
    int wv = threadIdx.x >> 6;
    int node = blockIdx.x * 2 + wv;
    if (node >= N) return;
    int lane = threadIdx.x & 63;
    int d0 = lane * 2;
    float2 lwv = *(const float2*)(lw + d0);
    float2 lbv = *(const float2*)(lb + d0);
    int s0 = offs[node], s1 = offs[node + 1];
    int cnt = s1 - s0;
    float a0 = 0.f, a1 = 0.f;

    int2 pa = sedge[s0];
    int2 pb = (cnt > 1) ? sedge[s0 + 1] : pa;
    float2 ha = *(const float2*)(hprev + (size_t)pa.x * DIM + d0);
    float2 hb = *(const float2*)(hprev + (size_t)pb.x * DIM + d0);
    int i = s0;
    for (; i + 2 < s1; i += 2) {
        int2 na = sedge[i + 2];
        int2 nb = (i + 3 < s1) ? sedge[i + 3] : na;
        float2 hna = *(const float2*)(hprev + (size_t)na.x * DIM + d0);
        float2 hnb = *(const float2*)(hprev + (size_t)nb.x * DIM + d0);
        float wa = __int_as_float(pa.y), wb = __int_as_float(pb.y);
        a0 += fmaxf(ha.x + wa * lwv.x + lbv.x, 0.f);
        a1 += fmaxf(ha.y + wa * lwv.y + lbv.y, 0.f);
        a0 += fmaxf(hb.x + wb * lwv.x + lbv.x, 0.f);
        a1 += fmaxf(hb.y + wb * lwv.y + lbv.y, 0.f);
        pa = na; pb = nb; ha = hna; hb = hnb;
    }
    {
        float wa = __int_as_float(pa.y);
        a0 += fmaxf(ha.x + wa * lwv.x + lbv.x, 0.f);
        a1 += fmaxf(ha.y + wa * lwv.y + lbv.y, 0.f);
        if (i + 1 < s1) {
            float wb = __int_as_float(pb.y);
            a0 += fmaxf(hb.x + wb * lwv.x + lbv.x, 0.f);
            a1 += fmaxf(hb.y + wb * lwv.y + lbv.y, 0.f);
        }
    }
    float inv = 1.f / (float)cnt;
    float ge = 1.f + epsp[layer];
    float2 hs = *(const float2*)(hprev + (size_t)node * DIM + d0);
    float2 o;
    o.x = a0 * inv + ge * hs.x;
    o.y = a1 * inv + ge * hs.y;
    *(float2*)(outb + (size_t)node * DIM + d0) = o;
}

// ---------------- register-tiled GEMM, double-buffered ----------------
// tile: 64 nodes x 128 cols, 256 threads, thread = 4 nodes x 8 cols
// (cols cg*4..+3 and 64+cg*4..+3 -> s_w reads 2-way bank aliased = free).
// KT=32 chunks; next chunk staged global->regs during compute, regs->LDS
// after compute, single barrier per chunk.
#define GT_KT 32
#define SA_STR 68
template <int NSRC, bool RELU>
__global__ __launch_bounds__(256) void gemm_kernel(
    const float* __restrict__ a0, const float* __restrict__ a1,
    const float* __restrict__ a2, const float* __restrict__ a3,
    const float* __restrict__ w, const float* __restrict__ bias,
    float* __restrict__ out, int N) {
    __shared__ float s_a[2][GT_KT][SA_STR];
    __shared__ float s_w[2][GT_KT][128];
    const float* srcs[4] = {a0, a1, a2, a3};
    int tid = threadIdx.x;
    int n0 = blockIdx.x * 64;
    int cg = tid & 15;   // cols cg*4..+3 and 64+cg*4..+3
    int ng = tid >> 4;   // nodes ng*4..+3
    int anode = tid >> 3;          // 0..31
    int akq = (tid & 7) * 4;       // 0,4,...,28

    float acc[4][8];
#pragma unroll
    for (int m = 0; m < 4; m++)
#pragma unroll
        for (int c = 0; c < 8; c++) acc[m][c] = 0.f;

    const int K = NSRC * 128;
    const int NC = K / GT_KT;

    float4 ra[2], rw[4];
    // load chunk 0
    {
        const float* asrc = srcs[0];
#pragma unroll
        for (int i = 0; i < 2; i++) {
            int node = anode + 32 * i;
            ra[i] = make_float4(0.f, 0.f, 0.f, 0.f);
            if (n0 + node < N)
                ra[i] = *(const float4*)(asrc + (size_t)(n0 + node) * 128 + akq);
        }
        const float4* wp = (const float4*)w;
#pragma unroll
        for (int i = 0; i < 4; i++) rw[i] = wp[tid + 256 * i];
    }
    // store chunk 0
    {
#pragma unroll
        for (int i = 0; i < 2; i++) {
            int node = anode + 32 * i;
            s_a[0][akq + 0][node] = ra[i].x;
            s_a[0][akq + 1][node] = ra[i].y;
            s_a[0][akq + 2][node] = ra[i].z;
            s_a[0][akq + 3][node] = ra[i].w;
        }
        float4* wd = (float4*)&s_w[0][0][0];
#pragma unroll
        for (int i = 0; i < 4; i++) wd[tid + 256 * i] = rw[i];
    }
    __syncthreads();

    for (int c = 0; c < NC; c++) {
        int nb = c & 1;
        if (c + 1 < NC) {
            int k0 = (c + 1) * GT_KT;
            const float* asrc = srcs[k0 >> 7];
            int kl = k0 & 127;
#pragma unroll
            for (int i = 0; i < 2; i++) {
                int node = anode + 32 * i;
                ra[i] = make_float4(0.f, 0.f, 0.f, 0.f);
                if (n0 + node < N)
                    ra[i] = *(const float4*)(asrc + (size_t)(n0 + node) * 128 + kl + akq);
            }
            const float4* wp = (const float4*)(w + (size_t)k0 * 128);
#pragma unroll
            for (int i = 0; i < 4; i++) rw[i] = wp[tid + 256 * i];
        }
#pragma unroll 8
        for (int k = 0; k < GT_KT; k++) {
            float af[4], wf[8];
            *(float4*)&af[0] = *(const float4*)&s_a[nb][k][ng * 4];
            *(float4*)&wf[0] = *(const float4*)&s_w[nb][k][cg * 4];
            *(float4*)&wf[4] = *(const float4*)&s_w[nb][k][64 + cg * 4];
#pragma unroll
            for (int m = 0; m < 4; m++)
#pragma unroll
                for (int cc = 0; cc < 8; cc++)
                    acc[m][cc] = fmaf(af[m], wf[cc], acc[m][cc]);
        }
        if (c + 1 < NC) {
            int b2 = nb ^ 1;
#pragma unroll
            for (int i = 0; i < 2; i++) {
                int node = anode + 32 * i;
                s_a[b2][akq + 0][node] = ra[i].x;
                s_a[b2][akq + 1][node] = ra[i].y;
                s_a[b2][akq + 2][node] = ra[i].z;
                s_a[b2][akq + 3][node] = ra[i].w;
            }
            float4* wd = (float4*)&s_w[b2][0][0];
#pragma unroll
            for (int i = 0; i < 4; i++) wd[tid + 256 * i] = rw[i];
        }
        __syncthreads();
    }

    float4 bv0 = *(const float4*)(bias + cg * 4);
    float4 bv1 = *(const float4*)(bias + 64 + cg * 4);
#pragma unroll
    for (int m = 0; m < 4; m++) {
        int node = n0 + ng * 4 + m;
        if (node < N) {
            float4 o0, o1;
            o0.x = acc[m][0] + bv0.x; o0.y = acc[m][1] + bv0.y;
            o0.z = acc[m][2] + bv0.z; o0.w = acc[m][3] + bv0.w;
            o1.x = acc[m][4] + bv1.x; o1.y = acc[m][5] + bv1.y;
            o1.z = acc[m][6] + bv1.z; o1.w = acc[m][7] + bv1.w;
            if (RELU) {
                o0.x = fmaxf(o0.x, 0.f); o0.y = fmaxf(o0.y, 0.f);
                o0.z = fmaxf(o0.z, 0.f); o0.w = fmaxf(o0.w, 0.f);
                o1.x = fmaxf(o1.x, 0.f); o1.y = fmaxf(o1.y, 0.f);
                o1.z = fmaxf(o1.z, 0.f); o1.w = fmaxf(o1.w, 0.f);
            }
            float* op = out + (size_t)node * 128;
            *(float4*)(op + cg * 4) = o0;
            *(float4*)(op + 64 + cg * 4) = o1;
        }
    }
}

extern "C" void kernel_launch(void* const* d_in, const int* in_sizes, int n_in,
                              void* d_out, int out_size, void* d_ws, size_t ws_size,
                              hipStream_t stream) {
    const float* x   = (const float*)d_in[0];
    const int* edge_index = (const int*)d_in[1];
    const float* ea  = (const float*)d_in[2];
    const float* lw  = (const float*)d_in[3];
    const float* lb  = (const float*)d_in[4];
    const float* eps = (const float*)d_in[5];
    const float* w1  = (const float*)d_in[6];
    const float* b1  = (const float*)d_in[7];
    const float* w2  = (const float*)d_in[8];
    const float* b2  = (const float*)d_in[9];
    const float* fw  = (const float*)d_in[10];
    const float* fb  = (const float*)d_in[11];
    float* out = (float*)d_out;

    const int N = NN, E = NE;
    const int* src = edge_index;
    const int* tgt = edge_index + E;
    const int NB = (N + 1023) / 1024;  // 49

    char* ws = (char*)d_ws;
    size_t off = 0;
    auto alloc = [&](size_t bytes) {
        void* p = ws + off;
        off += (bytes + 255) & ~(size_t)255;
        return p;
    };
    int*   counts  = (int*)alloc((size_t)N * 4);
    int*   offsets = (int*)alloc((size_t)(N + 1) * 4);
    int*   cursor  = (int*)alloc((size_t)N * 4);
    int*   psum    = (int*)alloc((size_t)NB * 4);
    int*   pbase   = (int*)alloc((size_t)NB * 4);
    int2*  sedge   = (int2*)alloc((size_t)E * 8);
    float* hbuf[3];
    for (int i = 0; i < 3; i++) hbuf[i] = (float*)alloc((size_t)N * DIM * 4);
    float* outb = (float*)alloc((size_t)N * DIM * 4);
    (void)ws_size; (void)in_sizes; (void)n_in; (void)out_size;

    hipMemsetAsync(counts, 0, (size_t)N * 4, stream);
    hist_kernel<<<(E + 255) / 256, 256, 0, stream>>>(tgt, counts, E);
    scan_partial_kernel<<<NB, 256, 0, stream>>>(counts, psum, N);
    scan_small_kernel<<<1, 64, 0, stream>>>(psum, pbase, offsets, NB, N);
    scan_apply_kernel<<<NB, 256, 0, stream>>>(counts, pbase, offsets, cursor, N);
    scatter_kernel<<<(E + 255) / 256, 256, 0, stream>>>(src, tgt, ea, cursor, sedge, E);

    const int GB = (N + 63) / 64;  // 782
    for (int l = 0; l < NLAYERS; l++) {
        const float* hin = (l == 0) ? x : hbuf[l - 1];
        agg_kernel<<<(N + 1) / 2, 128, 0, stream>>>(hin, offsets, sedge,
            lw + l * DIM, lb + l * DIM, eps, l, outb, N);
        gemm_kernel<1, true><<<GB, 256, 0, stream>>>(
            outb, nullptr, nullptr, nullptr,
            w1 + (size_t)l * DIM * DIM, b1 + l * DIM, outb, N);
        gemm_kernel<1, false><<<GB, 256, 0, stream>>>(
            outb, nullptr, nullptr, nullptr,
            w2 + (size_t)l * DIM * DIM, b2 + l * DIM, hbuf[l], N);
    }
    gemm_kernel<4, false><<<GB, 256, 0, stream>>>(
        x, hbuf[0], hbuf[1], hbuf[2], fw, fb, out, N);
}

// Round 5
// 510.992 us; speedup vs baseline: 1.3693x; 1.3693x over previous
//
#include <hip/hip_runtime.h>

#define NN 50000
#define NE 800000
#define DIM 128
#define NLAYERS 3

typedef __attribute__((ext_vector_type(8))) short bf16x8;
typedef __attribute__((ext_vector_type(4))) float f32x4;

__device__ __forceinline__ unsigned short f2bf_hi(float f) {
    unsigned int u = __float_as_uint(f);
    u += 0x7FFF + ((u >> 16) & 1);   // RTNE
    return (unsigned short)(u >> 16);
}
__device__ __forceinline__ float bf2f(unsigned short u) {
    return __uint_as_float(((unsigned int)u) << 16);
}

// ---------------- CSR build ----------------
__global__ void hist_kernel(const int* __restrict__ tgt, int* __restrict__ counts, int E) {
    int e = blockIdx.x * blockDim.x + threadIdx.x;
    if (e < E) atomicAdd(&counts[tgt[e]], 1);
}

__global__ __launch_bounds__(256) void scan_partial_kernel(const int* __restrict__ counts,
                                                           int* __restrict__ psum, int n) {
    __shared__ int ws[4];
    int b = blockIdx.x, t = threadIdx.x;
    int idx = b * 1024 + t * 4;
    int v = 0;
    if (idx < n) {
        int4 c = *(const int4*)(counts + idx);
        v = c.x + c.y + c.z + c.w;
    }
#pragma unroll
    for (int o = 32; o > 0; o >>= 1) v += __shfl_xor(v, o);
    int lane = t & 63, wid = t >> 6;
    if (lane == 0) ws[wid] = v;
    __syncthreads();
    if (t == 0) psum[b] = ws[0] + ws[1] + ws[2] + ws[3];
}

__global__ __launch_bounds__(64) void scan_small_kernel(const int* __restrict__ psum,
                                                        int* __restrict__ pbase,
                                                        int* __restrict__ offsets,
                                                        int nb, int n) {
    int lane = threadIdx.x;
    int v = (lane < nb) ? psum[lane] : 0;
    int incl = v;
#pragma unroll
    for (int o = 1; o < 64; o <<= 1) {
        int t = __shfl_up(incl, o);
        if (lane >= o) incl += t;
    }
    if (lane < nb) pbase[lane] = incl - v;
    if (lane == 63) offsets[n] = incl;
}

__global__ __launch_bounds__(256) void scan_apply_kernel(const int* __restrict__ counts,
                                                         const int* __restrict__ pbase,
                                                         int* __restrict__ offsets,
                                                         int* __restrict__ cursor, int n) {
    __shared__ int ws[4];
    int b = blockIdx.x, t = threadIdx.x;
    int lane = t & 63, wid = t >> 6;
    int idx = b * 1024 + t * 4;
    int4 c = make_int4(0, 0, 0, 0);
    if (idx < n) c = *(const int4*)(counts + idx);
    int tsum = c.x + c.y + c.z + c.w;
    int incl = tsum;
#pragma unroll
    for (int o = 1; o < 64; o <<= 1) {
        int tt = __shfl_up(incl, o);
        if (lane >= o) incl += tt;
    }
    if (lane == 63) ws[wid] = incl;
    __syncthreads();
    int wbase = pbase[b];
    for (int w = 0; w < wid; w++) wbase += ws[w];
    if (idx < n) {
        int e0 = wbase + incl - tsum;
        int4 o;
        o.x = e0;
        o.y = e0 + c.x;
        o.z = o.y + c.y;
        o.w = o.z + c.z;
        *(int4*)(offsets + idx) = o;
        *(int4*)(cursor + idx) = o;
    }
}

__global__ void scatter_kernel(const int* __restrict__ src, const int* __restrict__ tgt,
                               const float* __restrict__ ea,
                               int* __restrict__ cursor, int2* __restrict__ sedge, int E) {
    int e = blockIdx.x * blockDim.x + threadIdx.x;
    if (e >= E) return;
    int t = tgt[e];
    int pos = atomicAdd(&cursor[t], 1);
    sedge[pos] = make_int2(src[e], __float_as_int(ea[e]));
}

// ---------------- per-layer aggregation ----------------
__global__ __launch_bounds__(128) void agg_kernel(
    const float* __restrict__ hprev, const int* __restrict__ offs,
    const int2* __restrict__ sedge,
    const float* __restrict__ lw, const float* __restrict__ lb,
    const float* __restrict__ epsp, int layer,
    float* __restrict__ outb, int N) {
    int wv = threadIdx.x >> 6;
    int node = blockIdx.x * 2 + wv;
    if (node >= N) return;
    int lane = threadIdx.x & 63;
    int d0 = lane * 2;
    float2 lwv = *(const float2*)(lw + d0);
    float2 lbv = *(const float2*)(lb + d0);
    int s0 = offs[node], s1 = offs[node + 1];
    int cnt = s1 - s0;
    float a0 = 0.f, a1 = 0.f;

    int2 pa = sedge[s0];
    int2 pb = (cnt > 1) ? sedge[s0 + 1] : pa;
    float2 ha = *(const float2*)(hprev + (size_t)pa.x * DIM + d0);
    float2 hb = *(const float2*)(hprev + (size_t)pb.x * DIM + d0);
    int i = s0;
    for (; i + 2 < s1; i += 2) {
        int2 na = sedge[i + 2];
        int2 nb = (i + 3 < s1) ? sedge[i + 3] : na;
        float2 hna = *(const float2*)(hprev + (size_t)na.x * DIM + d0);
        float2 hnb = *(const float2*)(hprev + (size_t)nb.x * DIM + d0);
        float wa = __int_as_float(pa.y), wb = __int_as_float(pb.y);
        a0 += fmaxf(ha.x + wa * lwv.x + lbv.x, 0.f);
        a1 += fmaxf(ha.y + wa * lwv.y + lbv.y, 0.f);
        a0 += fmaxf(hb.x + wb * lwv.x + lbv.x, 0.f);
        a1 += fmaxf(hb.y + wb * lwv.y + lbv.y, 0.f);
        pa = na; pb = nb; ha = hna; hb = hnb;
    }
    {
        float wa = __int_as_float(pa.y);
        a0 += fmaxf(ha.x + wa * lwv.x + lbv.x, 0.f);
        a1 += fmaxf(ha.y + wa * lwv.y + lbv.y, 0.f);
        if (i + 1 < s1) {
            float wb = __int_as_float(pb.y);
            a0 += fmaxf(hb.x + wb * lwv.x + lbv.x, 0.f);
            a1 += fmaxf(hb.y + wb * lwv.y + lbv.y, 0.f);
        }
    }
    float inv = 1.f / (float)cnt;
    float ge = 1.f + epsp[layer];
    float2 hs = *(const float2*)(hprev + (size_t)node * DIM + d0);
    float2 o;
    o.x = a0 * inv + ge * hs.x;
    o.y = a1 * inv + ge * hs.y;
    *(float2*)(outb + (size_t)node * DIM + d0) = o;
}

// ---------------- weight prep: fp32 [k][c] -> bf16 hi/lo transposed [c][k] ----------------
__global__ __launch_bounds__(256) void wprep_kernel(
    const float* __restrict__ w1, const float* __restrict__ w2, const float* __restrict__ fw,
    unsigned short* __restrict__ w1t_h, unsigned short* __restrict__ w1t_l,
    unsigned short* __restrict__ w2t_h, unsigned short* __restrict__ w2t_l,
    unsigned short* __restrict__ fwt_h, unsigned short* __restrict__ fwt_l) {
    int gid = blockIdx.x * 256 + threadIdx.x;
    float v; int oidx;
    unsigned short *oh, *ol;
    if (gid < 49152) {                       // w1 [3][128][128]
        int l = gid >> 14, rem = gid & 16383, k = rem >> 7, c = rem & 127;
        v = w1[gid]; oidx = l * 16384 + c * 128 + k; oh = w1t_h; ol = w1t_l;
    } else if (gid < 98304) {                // w2 [3][128][128]
        int g = gid - 49152;
        int l = g >> 14, rem = g & 16383, k = rem >> 7, c = rem & 127;
        v = w2[g]; oidx = l * 16384 + c * 128 + k; oh = w2t_h; ol = w2t_l;
    } else if (gid < 163840) {               // fw [512][128]
        int g = gid - 98304;
        int k = g >> 7, c = g & 127;
        v = fw[g]; oidx = c * 512 + k; oh = fwt_h; ol = fwt_l;
    } else return;
    unsigned short h = f2bf_hi(v);
    float lo = v - bf2f(h);
    oh[oidx] = h;
    ol[oidx] = f2bf_hi(lo);
}

// ---------------- MFMA GEMM (bf16x3 emulated fp32) ----------------
// Block: 256 thr (4 waves, 2x2), tile 64 nodes x 128 cols. Wave: 32x64 as
// 2x4 tiles of mfma_f32_16x16x32_bf16. A split hi/lo on the fly; W pre-split
// transposed [c][k]. LDS rows padded to 40 bf16 (80 B) -> 2-way bank alias.
#define AST 40
#define WST 40
template <int NSRC, bool RELU>
__global__ __launch_bounds__(256) void gemm_mfma(
    const float* __restrict__ a0, const float* __restrict__ a1,
    const float* __restrict__ a2, const float* __restrict__ a3,
    const unsigned short* __restrict__ wt_h, const unsigned short* __restrict__ wt_l,
    const float* __restrict__ bias, float* __restrict__ out, int N) {
    __shared__ unsigned short s_ah[64 * AST], s_al[64 * AST];
    __shared__ unsigned short s_wh[128 * WST], s_wl[128 * WST];
    const float* srcs[4] = {a0, a1, a2, a3};
    const int K = NSRC * 128;
    int tid = threadIdx.x;
    int n0 = blockIdx.x * 64;
    int lane = tid & 63, w = tid >> 6;
    int q = lane >> 4, lr = lane & 15;
    int wr = w >> 1, wc = w & 1;

    f32x4 acc[2][4];
#pragma unroll
    for (int i = 0; i < 2; i++)
#pragma unroll
        for (int j = 0; j < 4; j++) acc[i][j] = (f32x4)(0.f);

    int sar = tid >> 2;            // A row 0..63
    int sak = (tid & 3) * 8;       // A k offset 0/8/16/24
    int swc = tid >> 1;            // W col 0..127
    int sws = (tid & 1) * 16;      // W k offset 0/16

    for (int k0 = 0; k0 < K; k0 += 32) {
        // ---- stage A (fp32 -> bf16 hi/lo) ----
        const float* asrc = srcs[k0 >> 7];
        int kl = k0 & 127;
        float f[8] = {0.f, 0.f, 0.f, 0.f, 0.f, 0.f, 0.f, 0.f};
        if (n0 + sar < N) {
            const float* ap = asrc + (size_t)(n0 + sar) * 128 + kl + sak;
            float4 v0 = *(const float4*)ap;
            float4 v1 = *(const float4*)(ap + 4);
            f[0] = v0.x; f[1] = v0.y; f[2] = v0.z; f[3] = v0.w;
            f[4] = v1.x; f[5] = v1.y; f[6] = v1.z; f[7] = v1.w;
        }
        unsigned int uh[4], ul[4];
#pragma unroll
        for (int i = 0; i < 4; i++) {
            unsigned short h0 = f2bf_hi(f[2 * i]);
            unsigned short h1 = f2bf_hi(f[2 * i + 1]);
            unsigned short l0 = f2bf_hi(f[2 * i] - bf2f(h0));
            unsigned short l1 = f2bf_hi(f[2 * i + 1] - bf2f(h1));
            uh[i] = (unsigned int)h0 | ((unsigned int)h1 << 16);
            ul[i] = (unsigned int)l0 | ((unsigned int)l1 << 16);
        }
        *(uint4*)&s_ah[sar * AST + sak] = make_uint4(uh[0], uh[1], uh[2], uh[3]);
        *(uint4*)&s_al[sar * AST + sak] = make_uint4(ul[0], ul[1], ul[2], ul[3]);

        // ---- stage W (pre-split bf16, transposed [c][k]) ----
        {
            const unsigned short* wph = wt_h + (size_t)swc * K + k0 + sws;
            const unsigned short* wpl = wt_l + (size_t)swc * K + k0 + sws;
            uint4 h0 = *(const uint4*)wph;
            uint4 h1 = *(const uint4*)(wph + 8);
            uint4 l0 = *(const uint4*)wpl;
            uint4 l1 = *(const uint4*)(wpl + 8);
            *(uint4*)&s_wh[swc * WST + sws] = h0;
            *(uint4*)&s_wh[swc * WST + sws + 8] = h1;
            *(uint4*)&s_wl[swc * WST + sws] = l0;
            *(uint4*)&s_wl[swc * WST + sws + 8] = l1;
        }
        __syncthreads();

        // ---- fragments + MFMA ----
        bf16x8 ah[2], al_[2], bh[4], bl[4];
#pragma unroll
        for (int i = 0; i < 2; i++) {
            int row = wr * 32 + i * 16 + lr;
            ah[i]  = *(const bf16x8*)&s_ah[row * AST + q * 8];
            al_[i] = *(const bf16x8*)&s_al[row * AST + q * 8];
        }
#pragma unroll
        for (int j = 0; j < 4; j++) {
            int col = wc * 64 + j * 16 + lr;
            bh[j] = *(const bf16x8*)&s_wh[col * WST + q * 8];
            bl[j] = *(const bf16x8*)&s_wl[col * WST + q * 8];
        }
#pragma unroll
        for (int i = 0; i < 2; i++)
#pragma unroll
            for (int j = 0; j < 4; j++) {
                acc[i][j] = __builtin_amdgcn_mfma_f32_16x16x32_bf16(ah[i], bh[j], acc[i][j], 0, 0, 0);
                acc[i][j] = __builtin_amdgcn_mfma_f32_16x16x32_bf16(ah[i], bl[j], acc[i][j], 0, 0, 0);
                acc[i][j] = __builtin_amdgcn_mfma_f32_16x16x32_bf16(al_[i], bh[j], acc[i][j], 0, 0, 0);
            }
        __syncthreads();
    }

    // ---- epilogue: C/D layout col=lane&15, row=(lane>>4)*4+reg ----
#pragma unroll
    for (int i = 0; i < 2; i++) {
        int rbase = wr * 32 + i * 16 + q * 4;
#pragma unroll
        for (int j = 0; j < 4; j++) {
            int col = wc * 64 + j * 16 + lr;
            float bv = bias[col];
#pragma unroll
            for (int r = 0; r < 4; r++) {
                int node = n0 + rbase + r;
                if (node < N) {
                    float o = acc[i][j][r] + bv;
                    if (RELU) o = fmaxf(o, 0.f);
                    out[(size_t)node * 128 + col] = o;
                }
            }
        }
    }
}

extern "C" void kernel_launch(void* const* d_in, const int* in_sizes, int n_in,
                              void* d_out, int out_size, void* d_ws, size_t ws_size,
                              hipStream_t stream) {
    const float* x   = (const float*)d_in[0];
    const int* edge_index = (const int*)d_in[1];
    const float* ea  = (const float*)d_in[2];
    const float* lw  = (const float*)d_in[3];
    const float* lb  = (const float*)d_in[4];
    const float* eps = (const float*)d_in[5];
    const float* w1  = (const float*)d_in[6];
    const float* b1  = (const float*)d_in[7];
    const float* w2  = (const float*)d_in[8];
    const float* b2  = (const float*)d_in[9];
    const float* fw  = (const float*)d_in[10];
    const float* fb  = (const float*)d_in[11];
    float* out = (float*)d_out;

    const int N = NN, E = NE;
    const int* src = edge_index;
    const int* tgt = edge_index + E;
    const int NB = (N + 1023) / 1024;  // 49

    char* ws = (char*)d_ws;
    size_t off = 0;
    auto alloc = [&](size_t bytes) {
        void* p = ws + off;
        off += (bytes + 255) & ~(size_t)255;
        return p;
    };
    int*   counts  = (int*)alloc((size_t)N * 4);
    int*   offsets = (int*)alloc((size_t)(N + 1) * 4);
    int*   cursor  = (int*)alloc((size_t)N * 4);
    int*   psum    = (int*)alloc((size_t)NB * 4);
    int*   pbase   = (int*)alloc((size_t)NB * 4);
    int2*  sedge   = (int2*)alloc((size_t)E * 8);
    unsigned short* w1t_h = (unsigned short*)alloc(49152 * 2);
    unsigned short* w1t_l = (unsigned short*)alloc(49152 * 2);
    unsigned short* w2t_h = (unsigned short*)alloc(49152 * 2);
    unsigned short* w2t_l = (unsigned short*)alloc(49152 * 2);
    unsigned short* fwt_h = (unsigned short*)alloc(65536 * 2);
    unsigned short* fwt_l = (unsigned short*)alloc(65536 * 2);
    float* hbuf[3];
    for (int i = 0; i < 3; i++) hbuf[i] = (float*)alloc((size_t)N * DIM * 4);
    float* outb = (float*)alloc((size_t)N * DIM * 4);
    (void)ws_size; (void)in_sizes; (void)n_in; (void)out_size;

    hipMemsetAsync(counts, 0, (size_t)N * 4, stream);
    hist_kernel<<<(E + 255) / 256, 256, 0, stream>>>(tgt, counts, E);
    wprep_kernel<<<640, 256, 0, stream>>>(w1, w2, fw, w1t_h, w1t_l, w2t_h, w2t_l, fwt_h, fwt_l);
    scan_partial_kernel<<<NB, 256, 0, stream>>>(counts, psum, N);
    scan_small_kernel<<<1, 64, 0, stream>>>(psum, pbase, offsets, NB, N);
    scan_apply_kernel<<<NB, 256, 0, stream>>>(counts, pbase, offsets, cursor, N);
    scatter_kernel<<<(E + 255) / 256, 256, 0, stream>>>(src, tgt, ea, cursor, sedge, E);

    const int GB = (N + 63) / 64;  // 782
    for (int l = 0; l < NLAYERS; l++) {
        const float* hin = (l == 0) ? x : hbuf[l - 1];
        agg_kernel<<<(N + 1) / 2, 128, 0, stream>>>(hin, offsets, sedge,
            lw + l * DIM, lb + l * DIM, eps, l, outb, N);
        gemm_mfma<1, true><<<GB, 256, 0, stream>>>(
            outb, nullptr, nullptr, nullptr,
            w1t_h + l * 16384, w1t_l + l * 16384, b1 + l * DIM, outb, N);
        gemm_mfma<1, false><<<GB, 256, 0, stream>>>(
            outb, nullptr, nullptr, nullptr,
            w2t_h + l * 16384, w2t_l + l * 16384, b2 + l * DIM, hbuf[l], N);
    }
    gemm_mfma<4, false><<<GB, 256, 0, stream>>>(
        x, hbuf[0], hbuf[1], hbuf[2], fwt_h, fwt_l, fb, out, N);
}

// Round 6
// 498.419 us; speedup vs baseline: 1.4038x; 1.0252x over previous
//
#include <hip/hip_runtime.h>

#define NN 50000
#define NE 800000
#define DIM 128
#define NLAYERS 3

typedef __attribute__((ext_vector_type(8))) short bf16x8;
typedef __attribute__((ext_vector_type(4))) float f32x4;

__device__ __forceinline__ unsigned short f2bf_hi(float f) {
    unsigned int u = __float_as_uint(f);
    u += 0x7FFF + ((u >> 16) & 1);   // RTNE
    return (unsigned short)(u >> 16);
}
__device__ __forceinline__ float bf2f(unsigned short u) {
    return __uint_as_float(((unsigned int)u) << 16);
}

// ---------------- CSR build ----------------
__global__ void hist_kernel(const int* __restrict__ tgt, int* __restrict__ counts, int E) {
    int e = blockIdx.x * blockDim.x + threadIdx.x;
    if (e < E) atomicAdd(&counts[tgt[e]], 1);
}

__global__ __launch_bounds__(256) void scan_partial_kernel(const int* __restrict__ counts,
                                                           int* __restrict__ psum, int n) {
    __shared__ int ws[4];
    int b = blockIdx.x, t = threadIdx.x;
    int idx = b * 1024 + t * 4;
    int v = 0;
    if (idx < n) {
        int4 c = *(const int4*)(counts + idx);
        v = c.x + c.y + c.z + c.w;
    }
#pragma unroll
    for (int o = 32; o > 0; o >>= 1) v += __shfl_xor(v, o);
    int lane = t & 63, wid = t >> 6;
    if (lane == 0) ws[wid] = v;
    __syncthreads();
    if (t == 0) psum[b] = ws[0] + ws[1] + ws[2] + ws[3];
}

__global__ __launch_bounds__(64) void scan_small_kernel(const int* __restrict__ psum,
                                                        int* __restrict__ pbase,
                                                        int* __restrict__ offsets,
                                                        int nb, int n) {
    int lane = threadIdx.x;
    int v = (lane < nb) ? psum[lane] : 0;
    int incl = v;
#pragma unroll
    for (int o = 1; o < 64; o <<= 1) {
        int t = __shfl_up(incl, o);
        if (lane >= o) incl += t;
    }
    if (lane < nb) pbase[lane] = incl - v;
    if (lane == 63) offsets[n] = incl;
}

__global__ __launch_bounds__(256) void scan_apply_kernel(const int* __restrict__ counts,
                                                         const int* __restrict__ pbase,
                                                         int* __restrict__ offsets,
                                                         int* __restrict__ cursor, int n) {
    __shared__ int ws[4];
    int b = blockIdx.x, t = threadIdx.x;
    int lane = t & 63, wid = t >> 6;
    int idx = b * 1024 + t * 4;
    int4 c = make_int4(0, 0, 0, 0);
    if (idx < n) c = *(const int4*)(counts + idx);
    int tsum = c.x + c.y + c.z + c.w;
    int incl = tsum;
#pragma unroll
    for (int o = 1; o < 64; o <<= 1) {
        int tt = __shfl_up(incl, o);
        if (lane >= o) incl += tt;
    }
    if (lane == 63) ws[wid] = incl;
    __syncthreads();
    int wbase = pbase[b];
    for (int w = 0; w < wid; w++) wbase += ws[w];
    if (idx < n) {
        int e0 = wbase + incl - tsum;
        int4 o;
        o.x = e0;
        o.y = e0 + c.x;
        o.z = o.y + c.y;
        o.w = o.z + c.z;
        *(int4*)(offsets + idx) = o;
        *(int4*)(cursor + idx) = o;
    }
}

__global__ void scatter_kernel(const int* __restrict__ src, const int* __restrict__ tgt,
                               const float* __restrict__ ea,
                               int* __restrict__ cursor, int2* __restrict__ sedge, int E) {
    int e = blockIdx.x * blockDim.x + threadIdx.x;
    if (e >= E) return;
    int t = tgt[e];
    int pos = atomicAdd(&cursor[t], 1);
    sedge[pos] = make_int2(src[e], __float_as_int(ea[e]));
}

// ---------------- per-layer aggregation ----------------
// one wave per node; two half-waves own alternating edges (float4/lane over
// 32 lanes = full 512B row); depth-2 software pipeline => ~4 gathers in flight
__global__ __launch_bounds__(256) void agg_kernel(
    const float* __restrict__ hprev, const int* __restrict__ offs,
    const int2* __restrict__ sedge,
    const float* __restrict__ lw, const float* __restrict__ lb,
    const float* __restrict__ epsp, int layer,
    float* __restrict__ outb, int N) {
    int wv = threadIdx.x >> 6;
    int node = blockIdx.x * 4 + wv;
    if (node >= N) return;
    int lane = threadIdx.x & 63;
    int half = lane >> 5, sub = lane & 31;
    int d0 = sub * 4;
    float4 lwv = *(const float4*)(lw + d0);
    float4 lbv = *(const float4*)(lb + d0);
    int s0 = offs[node], s1 = offs[node + 1];
    int cnt = s1 - s0;
    float4 a = make_float4(0.f, 0.f, 0.f, 0.f);

    int i0 = s0 + half;
    int i1 = s0 + 2 + half;
    bool v0 = i0 < s1, v1 = i1 < s1;
    int2 e0 = sedge[min(i0, s1 - 1)];
    int2 e1 = sedge[min(i1, s1 - 1)];
    float4 h0 = *(const float4*)(hprev + (size_t)e0.x * DIM + d0);
    float4 h1 = *(const float4*)(hprev + (size_t)e1.x * DIM + d0);

    for (int it = s0; it < s1; it += 2) {
        int i2 = it + 4 + half;
        bool v2 = i2 < s1;
        int2 e2 = sedge[min(i2, s1 - 1)];
        float4 h2 = *(const float4*)(hprev + (size_t)e2.x * DIM + d0);
        if (v0) {
            float wgt = __int_as_float(e0.y);
            a.x += fmaxf(h0.x + wgt * lwv.x + lbv.x, 0.f);
            a.y += fmaxf(h0.y + wgt * lwv.y + lbv.y, 0.f);
            a.z += fmaxf(h0.z + wgt * lwv.z + lbv.z, 0.f);
            a.w += fmaxf(h0.w + wgt * lwv.w + lbv.w, 0.f);
        }
        e0 = e1; h0 = h1; v0 = v1;
        e1 = e2; h1 = h2; v1 = v2;
    }

    a.x += __shfl_xor(a.x, 32);
    a.y += __shfl_xor(a.y, 32);
    a.z += __shfl_xor(a.z, 32);
    a.w += __shfl_xor(a.w, 32);

    if (half == 0) {
        float inv = 1.f / (float)cnt;
        float ge = 1.f + epsp[layer];
        float4 hs = *(const float4*)(hprev + (size_t)node * DIM + d0);
        float4 o;
        o.x = a.x * inv + ge * hs.x;
        o.y = a.y * inv + ge * hs.y;
        o.z = a.z * inv + ge * hs.z;
        o.w = a.w * inv + ge * hs.w;
        *(float4*)(outb + (size_t)node * DIM + d0) = o;
    }
}

// ---------------- weight prep: fp32 [k][c] -> bf16 hi/lo transposed [c][k] ----------------
__global__ __launch_bounds__(256) void wprep_kernel(
    const float* __restrict__ w1, const float* __restrict__ w2, const float* __restrict__ fw,
    unsigned short* __restrict__ w1t_h, unsigned short* __restrict__ w1t_l,
    unsigned short* __restrict__ w2t_h, unsigned short* __restrict__ w2t_l,
    unsigned short* __restrict__ fwt_h, unsigned short* __restrict__ fwt_l) {
    int gid = blockIdx.x * 256 + threadIdx.x;
    float v; int oidx;
    unsigned short *oh, *ol;
    if (gid < 49152) {                       // w1 [3][128][128]
        int l = gid >> 14, rem = gid & 16383, k = rem >> 7, c = rem & 127;
        v = w1[gid]; oidx = l * 16384 + c * 128 + k; oh = w1t_h; ol = w1t_l;
    } else if (gid < 98304) {                // w2 [3][128][128]
        int g = gid - 49152;
        int l = g >> 14, rem = g & 16383, k = rem >> 7, c = rem & 127;
        v = w2[g]; oidx = l * 16384 + c * 128 + k; oh = w2t_h; ol = w2t_l;
    } else if (gid < 163840) {               // fw [512][128]
        int g = gid - 98304;
        int k = g >> 7, c = g & 127;
        v = fw[g]; oidx = c * 512 + k; oh = fwt_h; ol = fwt_l;
    } else return;
    unsigned short h = f2bf_hi(v);
    float lo = v - bf2f(h);
    oh[oidx] = h;
    ol[oidx] = f2bf_hi(lo);
}

#define AST 40
#define WST 40

// ---------------- fused 2-layer MLP (bf16x3 MFMA) ----------------
// Block: 256 thr (2x2 waves), 64 nodes x 128 cols. Phase 1: hidden =
// relu(in@w1+b1) -> LDS fp32 (padded 132). Phase 2: out = hidden@w2+b2.
__global__ __launch_bounds__(256) void mlp_fused(
    const float* __restrict__ in,
    const unsigned short* __restrict__ w1h, const unsigned short* __restrict__ w1l,
    const float* __restrict__ b1,
    const unsigned short* __restrict__ w2h, const unsigned short* __restrict__ w2l,
    const float* __restrict__ b2,
    float* __restrict__ out, int N) {
    __shared__ float s_h[64][132];
    __shared__ unsigned short s_ah[64 * AST], s_al[64 * AST];
    __shared__ unsigned short s_wh[128 * WST], s_wl[128 * WST];
    int tid = threadIdx.x;
    int n0 = blockIdx.x * 64;
    int lane = tid & 63, w = tid >> 6;
    int q = lane >> 4, lr = lane & 15;
    int wr = w >> 1, wc = w & 1;
    int sar = tid >> 2, sak = (tid & 3) * 8;
    int swc = tid >> 1, sws = (tid & 1) * 16;

    f32x4 acc[2][4];
#pragma unroll
    for (int i = 0; i < 2; i++)
#pragma unroll
        for (int j = 0; j < 4; j++) acc[i][j] = (f32x4)(0.f);

    // ---------- phase 1: in @ w1 ----------
    for (int k0 = 0; k0 < 128; k0 += 32) {
        float f[8] = {0.f, 0.f, 0.f, 0.f, 0.f, 0.f, 0.f, 0.f};
        if (n0 + sar < NN) {
            const float* ap = in + (size_t)(n0 + sar) * 128 + k0 + sak;
            float4 v0 = *(const float4*)ap;
            float4 v1 = *(const float4*)(ap + 4);
            f[0] = v0.x; f[1] = v0.y; f[2] = v0.z; f[3] = v0.w;
            f[4] = v1.x; f[5] = v1.y; f[6] = v1.z; f[7] = v1.w;
        }
        unsigned int uh[4], ul[4];
#pragma unroll
        for (int i = 0; i < 4; i++) {
            unsigned short h0 = f2bf_hi(f[2 * i]);
            unsigned short h1 = f2bf_hi(f[2 * i + 1]);
            unsigned short l0 = f2bf_hi(f[2 * i] - bf2f(h0));
            unsigned short l1 = f2bf_hi(f[2 * i + 1] - bf2f(h1));
            uh[i] = (unsigned int)h0 | ((unsigned int)h1 << 16);
            ul[i] = (unsigned int)l0 | ((unsigned int)l1 << 16);
        }
        *(uint4*)&s_ah[sar * AST + sak] = make_uint4(uh[0], uh[1], uh[2], uh[3]);
        *(uint4*)&s_al[sar * AST + sak] = make_uint4(ul[0], ul[1], ul[2], ul[3]);
        {
            const unsigned short* wph = w1h + (size_t)swc * 128 + k0 + sws;
            const unsigned short* wpl = w1l + (size_t)swc * 128 + k0 + sws;
            uint4 h0 = *(const uint4*)wph;
            uint4 h1 = *(const uint4*)(wph + 8);
            uint4 l0 = *(const uint4*)wpl;
            uint4 l1 = *(const uint4*)(wpl + 8);
            *(uint4*)&s_wh[swc * WST + sws] = h0;
            *(uint4*)&s_wh[swc * WST + sws + 8] = h1;
            *(uint4*)&s_wl[swc * WST + sws] = l0;
            *(uint4*)&s_wl[swc * WST + sws + 8] = l1;
        }
        __syncthreads();
        bf16x8 ah[2], al_[2], bh[4], bl[4];
#pragma unroll
        for (int i = 0; i < 2; i++) {
            int row = wr * 32 + i * 16 + lr;
            ah[i]  = *(const bf16x8*)&s_ah[row * AST + q * 8];
            al_[i] = *(const bf16x8*)&s_al[row * AST + q * 8];
        }
#pragma unroll
        for (int j = 0; j < 4; j++) {
            int col = wc * 64 + j * 16 + lr;
            bh[j] = *(const bf16x8*)&s_wh[col * WST + q * 8];
            bl[j] = *(const bf16x8*)&s_wl[col * WST + q * 8];
        }
#pragma unroll
        for (int i = 0; i < 2; i++)
#pragma unroll
            for (int j = 0; j < 4; j++) {
                acc[i][j] = __builtin_amdgcn_mfma_f32_16x16x32_bf16(ah[i], bh[j], acc[i][j], 0, 0, 0);
                acc[i][j] = __builtin_amdgcn_mfma_f32_16x16x32_bf16(ah[i], bl[j], acc[i][j], 0, 0, 0);
                acc[i][j] = __builtin_amdgcn_mfma_f32_16x16x32_bf16(al_[i], bh[j], acc[i][j], 0, 0, 0);
            }
        __syncthreads();
    }
    // hidden -> LDS (relu + b1)
#pragma unroll
    for (int i = 0; i < 2; i++) {
        int rbase = wr * 32 + i * 16 + q * 4;
#pragma unroll
        for (int j = 0; j < 4; j++) {
            int col = wc * 64 + j * 16 + lr;
            float bv = b1[col];
#pragma unroll
            for (int r = 0; r < 4; r++)
                s_h[rbase + r][col] = fmaxf(acc[i][j][r] + bv, 0.f);
        }
    }
    __syncthreads();

    // ---------- phase 2: hidden @ w2 ----------
#pragma unroll
    for (int i = 0; i < 2; i++)
#pragma unroll
        for (int j = 0; j < 4; j++) acc[i][j] = (f32x4)(0.f);

    for (int k0 = 0; k0 < 128; k0 += 32) {
        float f[8];
        *(float4*)&f[0] = *(const float4*)&s_h[sar][k0 + sak];
        *(float4*)&f[4] = *(const float4*)&s_h[sar][k0 + sak + 4];
        unsigned int uh[4], ul[4];
#pragma unroll
        for (int i = 0; i < 4; i++) {
            unsigned short h0 = f2bf_hi(f[2 * i]);
            unsigned short h1 = f2bf_hi(f[2 * i + 1]);
            unsigned short l0 = f2bf_hi(f[2 * i] - bf2f(h0));
            unsigned short l1 = f2bf_hi(f[2 * i + 1] - bf2f(h1));
            uh[i] = (unsigned int)h0 | ((unsigned int)h1 << 16);
            ul[i] = (unsigned int)l0 | ((unsigned int)l1 << 16);
        }
        __syncthreads();   // ensure prior MFMA reads of s_ah done before overwrite
        *(uint4*)&s_ah[sar * AST + sak] = make_uint4(uh[0], uh[1], uh[2], uh[3]);
        *(uint4*)&s_al[sar * AST + sak] = make_uint4(ul[0], ul[1], ul[2], ul[3]);
        {
            const unsigned short* wph = w2h + (size_t)swc * 128 + k0 + sws;
            const unsigned short* wpl = w2l + (size_t)swc * 128 + k0 + sws;
            uint4 h0 = *(const uint4*)wph;
            uint4 h1 = *(const uint4*)(wph + 8);
            uint4 l0 = *(const uint4*)wpl;
            uint4 l1 = *(const uint4*)(wpl + 8);
            *(uint4*)&s_wh[swc * WST + sws] = h0;
            *(uint4*)&s_wh[swc * WST + sws + 8] = h1;
            *(uint4*)&s_wl[swc * WST + sws] = l0;
            *(uint4*)&s_wl[swc * WST + sws + 8] = l1;
        }
        __syncthreads();
        bf16x8 ah[2], al_[2], bh[4], bl[4];
#pragma unroll
        for (int i = 0; i < 2; i++) {
            int row = wr * 32 + i * 16 + lr;
            ah[i]  = *(const bf16x8*)&s_ah[row * AST + q * 8];
            al_[i] = *(const bf16x8*)&s_al[row * AST + q * 8];
        }
#pragma unroll
        for (int j = 0; j < 4; j++) {
            int col = wc * 64 + j * 16 + lr;
            bh[j] = *(const bf16x8*)&s_wh[col * WST + q * 8];
            bl[j] = *(const bf16x8*)&s_wl[col * WST + q * 8];
        }
#pragma unroll
        for (int i = 0; i < 2; i++)
#pragma unroll
            for (int j = 0; j < 4; j++) {
                acc[i][j] = __builtin_amdgcn_mfma_f32_16x16x32_bf16(ah[i], bh[j], acc[i][j], 0, 0, 0);
                acc[i][j] = __builtin_amdgcn_mfma_f32_16x16x32_bf16(ah[i], bl[j], acc[i][j], 0, 0, 0);
                acc[i][j] = __builtin_amdgcn_mfma_f32_16x16x32_bf16(al_[i], bh[j], acc[i][j], 0, 0, 0);
            }
    }

#pragma unroll
    for (int i = 0; i < 2; i++) {
        int rbase = wr * 32 + i * 16 + q * 4;
#pragma unroll
        for (int j = 0; j < 4; j++) {
            int col = wc * 64 + j * 16 + lr;
            float bv = b2[col];
#pragma unroll
            for (int r = 0; r < 4; r++) {
                int node = n0 + rbase + r;
                if (node < NN)
                    out[(size_t)node * 128 + col] = acc[i][j][r] + bv;
            }
        }
    }
}

// ---------------- 4-source MFMA GEMM for the final projection ----------------
template <int NSRC, bool RELU>
__global__ __launch_bounds__(256) void gemm_mfma(
    const float* __restrict__ a0, const float* __restrict__ a1,
    const float* __restrict__ a2, const float* __restrict__ a3,
    const unsigned short* __restrict__ wt_h, const unsigned short* __restrict__ wt_l,
    const float* __restrict__ bias, float* __restrict__ out, int N) {
    __shared__ unsigned short s_ah[64 * AST], s_al[64 * AST];
    __shared__ unsigned short s_wh[128 * WST], s_wl[128 * WST];
    const float* srcs[4] = {a0, a1, a2, a3};
    const int K = NSRC * 128;
    int tid = threadIdx.x;
    int n0 = blockIdx.x * 64;
    int lane = tid & 63, w = tid >> 6;
    int q = lane >> 4, lr = lane & 15;
    int wr = w >> 1, wc = w & 1;

    f32x4 acc[2][4];
#pragma unroll
    for (int i = 0; i < 2; i++)
#pragma unroll
        for (int j = 0; j < 4; j++) acc[i][j] = (f32x4)(0.f);

    int sar = tid >> 2;
    int sak = (tid & 3) * 8;
    int swc = tid >> 1;
    int sws = (tid & 1) * 16;

    for (int k0 = 0; k0 < K; k0 += 32) {
        const float* asrc = srcs[k0 >> 7];
        int kl = k0 & 127;
        float f[8] = {0.f, 0.f, 0.f, 0.f, 0.f, 0.f, 0.f, 0.f};
        if (n0 + sar < N) {
            const float* ap = asrc + (size_t)(n0 + sar) * 128 + kl + sak;
            float4 v0 = *(const float4*)ap;
            float4 v1 = *(const float4*)(ap + 4);
            f[0] = v0.x; f[1] = v0.y; f[2] = v0.z; f[3] = v0.w;
            f[4] = v1.x; f[5] = v1.y; f[6] = v1.z; f[7] = v1.w;
        }
        unsigned int uh[4], ul[4];
#pragma unroll
        for (int i = 0; i < 4; i++) {
            unsigned short h0 = f2bf_hi(f[2 * i]);
            unsigned short h1 = f2bf_hi(f[2 * i + 1]);
            unsigned short l0 = f2bf_hi(f[2 * i] - bf2f(h0));
            unsigned short l1 = f2bf_hi(f[2 * i + 1] - bf2f(h1));
            uh[i] = (unsigned int)h0 | ((unsigned int)h1 << 16);
            ul[i] = (unsigned int)l0 | ((unsigned int)l1 << 16);
        }
        *(uint4*)&s_ah[sar * AST + sak] = make_uint4(uh[0], uh[1], uh[2], uh[3]);
        *(uint4*)&s_al[sar * AST + sak] = make_uint4(ul[0], ul[1], ul[2], ul[3]);
        {
            const unsigned short* wph = wt_h + (size_t)swc * K + k0 + sws;
            const unsigned short* wpl = wt_l + (size_t)swc * K + k0 + sws;
            uint4 h0 = *(const uint4*)wph;
            uint4 h1 = *(const uint4*)(wph + 8);
            uint4 l0 = *(const uint4*)wpl;
            uint4 l1 = *(const uint4*)(wpl + 8);
            *(uint4*)&s_wh[swc * WST + sws] = h0;
            *(uint4*)&s_wh[swc * WST + sws + 8] = h1;
            *(uint4*)&s_wl[swc * WST + sws] = l0;
            *(uint4*)&s_wl[swc * WST + sws + 8] = l1;
        }
        __syncthreads();
        bf16x8 ah[2], al_[2], bh[4], bl[4];
#pragma unroll
        for (int i = 0; i < 2; i++) {
            int row = wr * 32 + i * 16 + lr;
            ah[i]  = *(const bf16x8*)&s_ah[row * AST + q * 8];
            al_[i] = *(const bf16x8*)&s_al[row * AST + q * 8];
        }
#pragma unroll
        for (int j = 0; j < 4; j++) {
            int col = wc * 64 + j * 16 + lr;
            bh[j] = *(const bf16x8*)&s_wh[col * WST + q * 8];
            bl[j] = *(const bf16x8*)&s_wl[col * WST + q * 8];
        }
#pragma unroll
        for (int i = 0; i < 2; i++)
#pragma unroll
            for (int j = 0; j < 4; j++) {
                acc[i][j] = __builtin_amdgcn_mfma_f32_16x16x32_bf16(ah[i], bh[j], acc[i][j], 0, 0, 0);
                acc[i][j] = __builtin_amdgcn_mfma_f32_16x16x32_bf16(ah[i], bl[j], acc[i][j], 0, 0, 0);
                acc[i][j] = __builtin_amdgcn_mfma_f32_16x16x32_bf16(al_[i], bh[j], acc[i][j], 0, 0, 0);
            }
        __syncthreads();
    }

#pragma unroll
    for (int i = 0; i < 2; i++) {
        int rbase = wr * 32 + i * 16 + q * 4;
#pragma unroll
        for (int j = 0; j < 4; j++) {
            int col = wc * 64 + j * 16 + lr;
            float bv = bias[col];
#pragma unroll
            for (int r = 0; r < 4; r++) {
                int node = n0 + rbase + r;
                if (node < N) {
                    float o = acc[i][j][r] + bv;
                    if (RELU) o = fmaxf(o, 0.f);
                    out[(size_t)node * 128 + col] = o;
                }
            }
        }
    }
}

extern "C" void kernel_launch(void* const* d_in, const int* in_sizes, int n_in,
                              void* d_out, int out_size, void* d_ws, size_t ws_size,
                              hipStream_t stream) {
    const float* x   = (const float*)d_in[0];
    const int* edge_index = (const int*)d_in[1];
    const float* ea  = (const float*)d_in[2];
    const float* lw  = (const float*)d_in[3];
    const float* lb  = (const float*)d_in[4];
    const float* eps = (const float*)d_in[5];
    const float* w1  = (const float*)d_in[6];
    const float* b1  = (const float*)d_in[7];
    const float* w2  = (const float*)d_in[8];
    const float* b2  = (const float*)d_in[9];
    const float* fw  = (const float*)d_in[10];
    const float* fb  = (const float*)d_in[11];
    float* out = (float*)d_out;

    const int N = NN, E = NE;
    const int* src = edge_index;
    const int* tgt = edge_index + E;
    const int NB = (N + 1023) / 1024;  // 49

    char* ws = (char*)d_ws;
    size_t off = 0;
    auto alloc = [&](size_t bytes) {
        void* p = ws + off;
        off += (bytes + 255) & ~(size_t)255;
        return p;
    };
    int*   counts  = (int*)alloc((size_t)N * 4);
    int*   offsets = (int*)alloc((size_t)(N + 1) * 4);
    int*   cursor  = (int*)alloc((size_t)N * 4);
    int*   psum    = (int*)alloc((size_t)NB * 4);
    int*   pbase   = (int*)alloc((size_t)NB * 4);
    int2*  sedge   = (int2*)alloc((size_t)E * 8);
    unsigned short* w1t_h = (unsigned short*)alloc(49152 * 2);
    unsigned short* w1t_l = (unsigned short*)alloc(49152 * 2);
    unsigned short* w2t_h = (unsigned short*)alloc(49152 * 2);
    unsigned short* w2t_l = (unsigned short*)alloc(49152 * 2);
    unsigned short* fwt_h = (unsigned short*)alloc(65536 * 2);
    unsigned short* fwt_l = (unsigned short*)alloc(65536 * 2);
    float* hbuf[3];
    for (int i = 0; i < 3; i++) hbuf[i] = (float*)alloc((size_t)N * DIM * 4);
    float* outb = (float*)alloc((size_t)N * DIM * 4);
    (void)ws_size; (void)in_sizes; (void)n_in; (void)out_size;

    hipMemsetAsync(counts, 0, (size_t)N * 4, stream);
    hist_kernel<<<(E + 255) / 256, 256, 0, stream>>>(tgt, counts, E);
    wprep_kernel<<<640, 256, 0, stream>>>(w1, w2, fw, w1t_h, w1t_l, w2t_h, w2t_l, fwt_h, fwt_l);
    scan_partial_kernel<<<NB, 256, 0, stream>>>(counts, psum, N);
    scan_small_kernel<<<1, 64, 0, stream>>>(psum, pbase, offsets, NB, N);
    scan_apply_kernel<<<NB, 256, 0, stream>>>(counts, pbase, offsets, cursor, N);
    scatter_kernel<<<(E + 255) / 256, 256, 0, stream>>>(src, tgt, ea, cursor, sedge, E);

    const int GB = (N + 63) / 64;  // 782
    for (int l = 0; l < NLAYERS; l++) {
        const float* hin = (l == 0) ? x : hbuf[l - 1];
        agg_kernel<<<(N + 3) / 4, 256, 0, stream>>>(hin, offsets, sedge,
            lw + l * DIM, lb + l * DIM, eps, l, outb, N);
        mlp_fused<<<GB, 256, 0, stream>>>(
            outb,
            w1t_h + l * 16384, w1t_l + l * 16384, b1 + l * DIM,
            w2t_h + l * 16384, w2t_l + l * 16384, b2 + l * DIM,
            hbuf[l], N);
    }
    gemm_mfma<4, false><<<GB, 256, 0, stream>>>(
        x, hbuf[0], hbuf[1], hbuf[2], fwt_h, fwt_l, fb, out, N);
}

// Round 7
// 468.685 us; speedup vs baseline: 1.4929x; 1.0634x over previous
//
#include <hip/hip_runtime.h>

#define NN 50000
#define NE 800000
#define DIM 128
#define NLAYERS 3

typedef __attribute__((ext_vector_type(8))) short bf16x8;
typedef __attribute__((ext_vector_type(4))) float f32x4;

__device__ __forceinline__ unsigned short f2bf_hi(float f) {
    unsigned int u = __float_as_uint(f);
    u += 0x7FFF + ((u >> 16) & 1);   // RTNE
    return (unsigned short)(u >> 16);
}
__device__ __forceinline__ float bf2f(unsigned short u) {
    return __uint_as_float(((unsigned int)u) << 16);
}

// ---------------- CSR build ----------------
__global__ void hist_kernel(const int* __restrict__ tgt, int* __restrict__ counts, int E) {
    int e = blockIdx.x * blockDim.x + threadIdx.x;
    if (e < E) atomicAdd(&counts[tgt[e]], 1);
}

__global__ __launch_bounds__(256) void scan_partial_kernel(const int* __restrict__ counts,
                                                           int* __restrict__ psum, int n) {
    __shared__ int ws[4];
    int b = blockIdx.x, t = threadIdx.x;
    int idx = b * 1024 + t * 4;
    int v = 0;
    if (idx < n) {
        int4 c = *(const int4*)(counts + idx);
        v = c.x + c.y + c.z + c.w;
    }
#pragma unroll
    for (int o = 32; o > 0; o >>= 1) v += __shfl_xor(v, o);
    int lane = t & 63, wid = t >> 6;
    if (lane == 0) ws[wid] = v;
    __syncthreads();
    if (t == 0) psum[b] = ws[0] + ws[1] + ws[2] + ws[3];
}

__global__ __launch_bounds__(64) void scan_small_kernel(const int* __restrict__ psum,
                                                        int* __restrict__ pbase,
                                                        int* __restrict__ offsets,
                                                        int nb, int n) {
    int lane = threadIdx.x;
    int v = (lane < nb) ? psum[lane] : 0;
    int incl = v;
#pragma unroll
    for (int o = 1; o < 64; o <<= 1) {
        int t = __shfl_up(incl, o);
        if (lane >= o) incl += t;
    }
    if (lane < nb) pbase[lane] = incl - v;
    if (lane == 63) offsets[n] = incl;
}

__global__ __launch_bounds__(256) void scan_apply_kernel(const int* __restrict__ counts,
                                                         const int* __restrict__ pbase,
                                                         int* __restrict__ offsets,
                                                         int* __restrict__ cursor, int n) {
    __shared__ int ws[4];
    int b = blockIdx.x, t = threadIdx.x;
    int lane = t & 63, wid = t >> 6;
    int idx = b * 1024 + t * 4;
    int4 c = make_int4(0, 0, 0, 0);
    if (idx < n) c = *(const int4*)(counts + idx);
    int tsum = c.x + c.y + c.z + c.w;
    int incl = tsum;
#pragma unroll
    for (int o = 1; o < 64; o <<= 1) {
        int tt = __shfl_up(incl, o);
        if (lane >= o) incl += tt;
    }
    if (lane == 63) ws[wid] = incl;
    __syncthreads();
    int wbase = pbase[b];
    for (int w = 0; w < wid; w++) wbase += ws[w];
    if (idx < n) {
        int e0 = wbase + incl - tsum;
        int4 o;
        o.x = e0;
        o.y = e0 + c.x;
        o.z = o.y + c.y;
        o.w = o.z + c.z;
        *(int4*)(offsets + idx) = o;
        *(int4*)(cursor + idx) = o;
    }
}

__global__ void scatter_kernel(const int* __restrict__ src, const int* __restrict__ tgt,
                               const float* __restrict__ ea,
                               int* __restrict__ cursor, int2* __restrict__ sedge, int E) {
    int e = blockIdx.x * blockDim.x + threadIdx.x;
    if (e >= E) return;
    int t = tgt[e];
    int pos = atomicAdd(&cursor[t], 1);
    sedge[pos] = make_int2(src[e], __float_as_int(ea[e]));
}

// ---------------- x -> bf16 convert ----------------
__global__ __launch_bounds__(256) void xcvt_kernel(const float* __restrict__ x,
                                                   unsigned short* __restrict__ xb, int n) {
    int i = (blockIdx.x * 256 + threadIdx.x) * 4;
    if (i >= n) return;
    float4 v = *(const float4*)(x + i);
    ushort4 o;
    o.x = f2bf_hi(v.x); o.y = f2bf_hi(v.y);
    o.z = f2bf_hi(v.z); o.w = f2bf_hi(v.w);
    *(ushort4*)(xb + i) = o;
}

// ---------------- per-layer aggregation (bf16 gather) ----------------
// one wave per node; two half-waves own alternating edges (ushort4/lane over
// 32 lanes = full 256B bf16 row); depth-2 pipeline => ~4 gathers in flight
__global__ __launch_bounds__(256) void agg_kernel(
    const unsigned short* __restrict__ hprev, const int* __restrict__ offs,
    const int2* __restrict__ sedge,
    const float* __restrict__ lw, const float* __restrict__ lb,
    const float* __restrict__ epsp, int layer,
    float* __restrict__ outb, int N) {
    int wv = threadIdx.x >> 6;
    int node = blockIdx.x * 4 + wv;
    if (node >= N) return;
    int lane = threadIdx.x & 63;
    int half = lane >> 5, sub = lane & 31;
    int d0 = sub * 4;
    float4 lwv = *(const float4*)(lw + d0);
    float4 lbv = *(const float4*)(lb + d0);
    int s0 = offs[node], s1 = offs[node + 1];
    int cnt = s1 - s0;
    float4 a = make_float4(0.f, 0.f, 0.f, 0.f);

    int i0 = s0 + half;
    int i1 = s0 + 2 + half;
    bool v0 = i0 < s1, v1 = i1 < s1;
    int2 e0 = sedge[min(i0, s1 - 1)];
    int2 e1 = sedge[min(i1, s1 - 1)];
    ushort4 h0 = *(const ushort4*)(hprev + (size_t)e0.x * DIM + d0);
    ushort4 h1 = *(const ushort4*)(hprev + (size_t)e1.x * DIM + d0);

    for (int it = s0; it < s1; it += 2) {
        int i2 = it + 4 + half;
        bool v2 = i2 < s1;
        int2 e2 = sedge[min(i2, s1 - 1)];
        ushort4 h2 = *(const ushort4*)(hprev + (size_t)e2.x * DIM + d0);
        if (v0) {
            float wgt = __int_as_float(e0.y);
            a.x += fmaxf(bf2f(h0.x) + wgt * lwv.x + lbv.x, 0.f);
            a.y += fmaxf(bf2f(h0.y) + wgt * lwv.y + lbv.y, 0.f);
            a.z += fmaxf(bf2f(h0.z) + wgt * lwv.z + lbv.z, 0.f);
            a.w += fmaxf(bf2f(h0.w) + wgt * lwv.w + lbv.w, 0.f);
        }
        e0 = e1; h0 = h1; v0 = v1;
        e1 = e2; h1 = h2; v1 = v2;
    }

    a.x += __shfl_xor(a.x, 32);
    a.y += __shfl_xor(a.y, 32);
    a.z += __shfl_xor(a.z, 32);
    a.w += __shfl_xor(a.w, 32);

    if (half == 0) {
        float inv = 1.f / (float)cnt;
        float ge = 1.f + epsp[layer];
        ushort4 hs = *(const ushort4*)(hprev + (size_t)node * DIM + d0);
        float4 o;
        o.x = a.x * inv + ge * bf2f(hs.x);
        o.y = a.y * inv + ge * bf2f(hs.y);
        o.z = a.z * inv + ge * bf2f(hs.z);
        o.w = a.w * inv + ge * bf2f(hs.w);
        *(float4*)(outb + (size_t)node * DIM + d0) = o;
    }
}

// ---------------- weight prep: fp32 [k][c] -> bf16 hi/lo transposed [c][k] ----------------
__global__ __launch_bounds__(256) void wprep_kernel(
    const float* __restrict__ w1, const float* __restrict__ w2, const float* __restrict__ fw,
    unsigned short* __restrict__ w1t_h, unsigned short* __restrict__ w1t_l,
    unsigned short* __restrict__ w2t_h, unsigned short* __restrict__ w2t_l,
    unsigned short* __restrict__ fwt_h, unsigned short* __restrict__ fwt_l) {
    int gid = blockIdx.x * 256 + threadIdx.x;
    float v; int oidx;
    unsigned short *oh, *ol;
    if (gid < 49152) {                       // w1 [3][128][128]
        int l = gid >> 14, rem = gid & 16383, k = rem >> 7, c = rem & 127;
        v = w1[gid]; oidx = l * 16384 + c * 128 + k; oh = w1t_h; ol = w1t_l;
    } else if (gid < 98304) {                // w2 [3][128][128]
        int g = gid - 49152;
        int l = g >> 14, rem = g & 16383, k = rem >> 7, c = rem & 127;
        v = w2[g]; oidx = l * 16384 + c * 128 + k; oh = w2t_h; ol = w2t_l;
    } else if (gid < 163840) {               // fw [512][128]
        int g = gid - 98304;
        int k = g >> 7, c = g & 127;
        v = fw[g]; oidx = c * 512 + k; oh = fwt_h; ol = fwt_l;
    } else return;
    unsigned short h = f2bf_hi(v);
    float lo = v - bf2f(h);
    oh[oidx] = h;
    ol[oidx] = f2bf_hi(lo);
}

#define AST 40
#define WST 40

// ---------------- fused 2-layer MLP (bf16x3 MFMA), bf16 output ----------------
__global__ __launch_bounds__(256) void mlp_fused(
    const float* __restrict__ in,
    const unsigned short* __restrict__ w1h, const unsigned short* __restrict__ w1l,
    const float* __restrict__ b1,
    const unsigned short* __restrict__ w2h, const unsigned short* __restrict__ w2l,
    const float* __restrict__ b2,
    unsigned short* __restrict__ out, int N) {
    __shared__ float s_h[64][132];
    __shared__ unsigned short s_ah[64 * AST], s_al[64 * AST];
    __shared__ unsigned short s_wh[128 * WST], s_wl[128 * WST];
    int tid = threadIdx.x;
    int n0 = blockIdx.x * 64;
    int lane = tid & 63, w = tid >> 6;
    int q = lane >> 4, lr = lane & 15;
    int wr = w >> 1, wc = w & 1;
    int sar = tid >> 2, sak = (tid & 3) * 8;
    int swc = tid >> 1, sws = (tid & 1) * 16;

    f32x4 acc[2][4];
#pragma unroll
    for (int i = 0; i < 2; i++)
#pragma unroll
        for (int j = 0; j < 4; j++) acc[i][j] = (f32x4)(0.f);

    // ---------- phase 1: in @ w1 ----------
    for (int k0 = 0; k0 < 128; k0 += 32) {
        float f[8] = {0.f, 0.f, 0.f, 0.f, 0.f, 0.f, 0.f, 0.f};
        if (n0 + sar < NN) {
            const float* ap = in + (size_t)(n0 + sar) * 128 + k0 + sak;
            float4 v0 = *(const float4*)ap;
            float4 v1 = *(const float4*)(ap + 4);
            f[0] = v0.x; f[1] = v0.y; f[2] = v0.z; f[3] = v0.w;
            f[4] = v1.x; f[5] = v1.y; f[6] = v1.z; f[7] = v1.w;
        }
        unsigned int uh[4], ul[4];
#pragma unroll
        for (int i = 0; i < 4; i++) {
            unsigned short h0 = f2bf_hi(f[2 * i]);
            unsigned short h1 = f2bf_hi(f[2 * i + 1]);
            unsigned short l0 = f2bf_hi(f[2 * i] - bf2f(h0));
            unsigned short l1 = f2bf_hi(f[2 * i + 1] - bf2f(h1));
            uh[i] = (unsigned int)h0 | ((unsigned int)h1 << 16);
            ul[i] = (unsigned int)l0 | ((unsigned int)l1 << 16);
        }
        *(uint4*)&s_ah[sar * AST + sak] = make_uint4(uh[0], uh[1], uh[2], uh[3]);
        *(uint4*)&s_al[sar * AST + sak] = make_uint4(ul[0], ul[1], ul[2], ul[3]);
        {
            const unsigned short* wph = w1h + (size_t)swc * 128 + k0 + sws;
            const unsigned short* wpl = w1l + (size_t)swc * 128 + k0 + sws;
            uint4 h0 = *(const uint4*)wph;
            uint4 h1 = *(const uint4*)(wph + 8);
            uint4 l0 = *(const uint4*)wpl;
            uint4 l1 = *(const uint4*)(wpl + 8);
            *(uint4*)&s_wh[swc * WST + sws] = h0;
            *(uint4*)&s_wh[swc * WST + sws + 8] = h1;
            *(uint4*)&s_wl[swc * WST + sws] = l0;
            *(uint4*)&s_wl[swc * WST + sws + 8] = l1;
        }
        __syncthreads();
        bf16x8 ah[2], al_[2], bh[4], bl[4];
#pragma unroll
        for (int i = 0; i < 2; i++) {
            int row = wr * 32 + i * 16 + lr;
            ah[i]  = *(const bf16x8*)&s_ah[row * AST + q * 8];
            al_[i] = *(const bf16x8*)&s_al[row * AST + q * 8];
        }
#pragma unroll
        for (int j = 0; j < 4; j++) {
            int col = wc * 64 + j * 16 + lr;
            bh[j] = *(const bf16x8*)&s_wh[col * WST + q * 8];
            bl[j] = *(const bf16x8*)&s_wl[col * WST + q * 8];
        }
#pragma unroll
        for (int i = 0; i < 2; i++)
#pragma unroll
            for (int j = 0; j < 4; j++) {
                acc[i][j] = __builtin_amdgcn_mfma_f32_16x16x32_bf16(ah[i], bh[j], acc[i][j], 0, 0, 0);
                acc[i][j] = __builtin_amdgcn_mfma_f32_16x16x32_bf16(ah[i], bl[j], acc[i][j], 0, 0, 0);
                acc[i][j] = __builtin_amdgcn_mfma_f32_16x16x32_bf16(al_[i], bh[j], acc[i][j], 0, 0, 0);
            }
        __syncthreads();
    }
    // hidden -> LDS (relu + b1)
#pragma unroll
    for (int i = 0; i < 2; i++) {
        int rbase = wr * 32 + i * 16 + q * 4;
#pragma unroll
        for (int j = 0; j < 4; j++) {
            int col = wc * 64 + j * 16 + lr;
            float bv = b1[col];
#pragma unroll
            for (int r = 0; r < 4; r++)
                s_h[rbase + r][col] = fmaxf(acc[i][j][r] + bv, 0.f);
        }
    }
    __syncthreads();

    // ---------- phase 2: hidden @ w2 ----------
#pragma unroll
    for (int i = 0; i < 2; i++)
#pragma unroll
        for (int j = 0; j < 4; j++) acc[i][j] = (f32x4)(0.f);

    for (int k0 = 0; k0 < 128; k0 += 32) {
        float f[8];
        *(float4*)&f[0] = *(const float4*)&s_h[sar][k0 + sak];
        *(float4*)&f[4] = *(const float4*)&s_h[sar][k0 + sak + 4];
        unsigned int uh[4], ul[4];
#pragma unroll
        for (int i = 0; i < 4; i++) {
            unsigned short h0 = f2bf_hi(f[2 * i]);
            unsigned short h1 = f2bf_hi(f[2 * i + 1]);
            unsigned short l0 = f2bf_hi(f[2 * i] - bf2f(h0));
            unsigned short l1 = f2bf_hi(f[2 * i + 1] - bf2f(h1));
            uh[i] = (unsigned int)h0 | ((unsigned int)h1 << 16);
            ul[i] = (unsigned int)l0 | ((unsigned int)l1 << 16);
        }
        __syncthreads();   // prior MFMA reads of s_ah done before overwrite
        *(uint4*)&s_ah[sar * AST + sak] = make_uint4(uh[0], uh[1], uh[2], uh[3]);
        *(uint4*)&s_al[sar * AST + sak] = make_uint4(ul[0], ul[1], ul[2], ul[3]);
        {
            const unsigned short* wph = w2h + (size_t)swc * 128 + k0 + sws;
            const unsigned short* wpl = w2l + (size_t)swc * 128 + k0 + sws;
            uint4 h0 = *(const uint4*)wph;
            uint4 h1 = *(const uint4*)(wph + 8);
            uint4 l0 = *(const uint4*)wpl;
            uint4 l1 = *(const uint4*)(wpl + 8);
            *(uint4*)&s_wh[swc * WST + sws] = h0;
            *(uint4*)&s_wh[swc * WST + sws + 8] = h1;
            *(uint4*)&s_wl[swc * WST + sws] = l0;
            *(uint4*)&s_wl[swc * WST + sws + 8] = l1;
        }
        __syncthreads();
        bf16x8 ah[2], al_[2], bh[4], bl[4];
#pragma unroll
        for (int i = 0; i < 2; i++) {
            int row = wr * 32 + i * 16 + lr;
            ah[i]  = *(const bf16x8*)&s_ah[row * AST + q * 8];
            al_[i] = *(const bf16x8*)&s_al[row * AST + q * 8];
        }
#pragma unroll
        for (int j = 0; j < 4; j++) {
            int col = wc * 64 + j * 16 + lr;
            bh[j] = *(const bf16x8*)&s_wh[col * WST + q * 8];
            bl[j] = *(const bf16x8*)&s_wl[col * WST + q * 8];
        }
#pragma unroll
        for (int i = 0; i < 2; i++)
#pragma unroll
            for (int j = 0; j < 4; j++) {
                acc[i][j] = __builtin_amdgcn_mfma_f32_16x16x32_bf16(ah[i], bh[j], acc[i][j], 0, 0, 0);
                acc[i][j] = __builtin_amdgcn_mfma_f32_16x16x32_bf16(ah[i], bl[j], acc[i][j], 0, 0, 0);
                acc[i][j] = __builtin_amdgcn_mfma_f32_16x16x32_bf16(al_[i], bh[j], acc[i][j], 0, 0, 0);
            }
    }

#pragma unroll
    for (int i = 0; i < 2; i++) {
        int rbase = wr * 32 + i * 16 + q * 4;
#pragma unroll
        for (int j = 0; j < 4; j++) {
            int col = wc * 64 + j * 16 + lr;
            float bv = b2[col];
#pragma unroll
            for (int r = 0; r < 4; r++) {
                int node = n0 + rbase + r;
                if (node < NN)
                    out[(size_t)node * 128 + col] = f2bf_hi(acc[i][j][r] + bv);
            }
        }
    }
}

// ---------------- final projection: 4 bf16 sources, B hi/lo ----------------
__global__ __launch_bounds__(256) void final_mfma(
    const unsigned short* __restrict__ a0, const unsigned short* __restrict__ a1,
    const unsigned short* __restrict__ a2, const unsigned short* __restrict__ a3,
    const unsigned short* __restrict__ wt_h, const unsigned short* __restrict__ wt_l,
    const float* __restrict__ bias, float* __restrict__ out, int N) {
    __shared__ unsigned short s_ah[64 * AST];
    __shared__ unsigned short s_wh[128 * WST], s_wl[128 * WST];
    const unsigned short* srcs[4] = {a0, a1, a2, a3};
    const int K = 512;
    int tid = threadIdx.x;
    int n0 = blockIdx.x * 64;
    int lane = tid & 63, w = tid >> 6;
    int q = lane >> 4, lr = lane & 15;
    int wr = w >> 1, wc = w & 1;

    f32x4 acc[2][4];
#pragma unroll
    for (int i = 0; i < 2; i++)
#pragma unroll
        for (int j = 0; j < 4; j++) acc[i][j] = (f32x4)(0.f);

    int sar = tid >> 2;
    int sak = (tid & 3) * 8;
    int swc = tid >> 1;
    int sws = (tid & 1) * 16;

    for (int k0 = 0; k0 < K; k0 += 32) {
        const unsigned short* asrc = srcs[k0 >> 7];
        int kl = k0 & 127;
        uint4 av = make_uint4(0, 0, 0, 0);
        if (n0 + sar < N)
            av = *(const uint4*)(asrc + (size_t)(n0 + sar) * 128 + kl + sak);
        *(uint4*)&s_ah[sar * AST + sak] = av;
        {
            const unsigned short* wph = wt_h + (size_t)swc * K + k0 + sws;
            const unsigned short* wpl = wt_l + (size_t)swc * K + k0 + sws;
            uint4 h0 = *(const uint4*)wph;
            uint4 h1 = *(const uint4*)(wph + 8);
            uint4 l0 = *(const uint4*)wpl;
            uint4 l1 = *(const uint4*)(wpl + 8);
            *(uint4*)&s_wh[swc * WST + sws] = h0;
            *(uint4*)&s_wh[swc * WST + sws + 8] = h1;
            *(uint4*)&s_wl[swc * WST + sws] = l0;
            *(uint4*)&s_wl[swc * WST + sws + 8] = l1;
        }
        __syncthreads();
        bf16x8 ah[2], bh[4], bl[4];
#pragma unroll
        for (int i = 0; i < 2; i++) {
            int row = wr * 32 + i * 16 + lr;
            ah[i] = *(const bf16x8*)&s_ah[row * AST + q * 8];
        }
#pragma unroll
        for (int j = 0; j < 4; j++) {
            int col = wc * 64 + j * 16 + lr;
            bh[j] = *(const bf16x8*)&s_wh[col * WST + q * 8];
            bl[j] = *(const bf16x8*)&s_wl[col * WST + q * 8];
        }
#pragma unroll
        for (int i = 0; i < 2; i++)
#pragma unroll
            for (int j = 0; j < 4; j++) {
                acc[i][j] = __builtin_amdgcn_mfma_f32_16x16x32_bf16(ah[i], bh[j], acc[i][j], 0, 0, 0);
                acc[i][j] = __builtin_amdgcn_mfma_f32_16x16x32_bf16(ah[i], bl[j], acc[i][j], 0, 0, 0);
            }
        __syncthreads();
    }

#pragma unroll
    for (int i = 0; i < 2; i++) {
        int rbase = wr * 32 + i * 16 + q * 4;
#pragma unroll
        for (int j = 0; j < 4; j++) {
            int col = wc * 64 + j * 16 + lr;
            float bv = bias[col];
#pragma unroll
            for (int r = 0; r < 4; r++) {
                int node = n0 + rbase + r;
                if (node < N)
                    out[(size_t)node * 128 + col] = acc[i][j][r] + bv;
            }
        }
    }
}

extern "C" void kernel_launch(void* const* d_in, const int* in_sizes, int n_in,
                              void* d_out, int out_size, void* d_ws, size_t ws_size,
                              hipStream_t stream) {
    const float* x   = (const float*)d_in[0];
    const int* edge_index = (const int*)d_in[1];
    const float* ea  = (const float*)d_in[2];
    const float* lw  = (const float*)d_in[3];
    const float* lb  = (const float*)d_in[4];
    const float* eps = (const float*)d_in[5];
    const float* w1  = (const float*)d_in[6];
    const float* b1  = (const float*)d_in[7];
    const float* w2  = (const float*)d_in[8];
    const float* b2  = (const float*)d_in[9];
    const float* fw  = (const float*)d_in[10];
    const float* fb  = (const float*)d_in[11];
    float* out = (float*)d_out;

    const int N = NN, E = NE;
    const int* src = edge_index;
    const int* tgt = edge_index + E;
    const int NB = (N + 1023) / 1024;  // 49

    char* ws = (char*)d_ws;
    size_t off = 0;
    auto alloc = [&](size_t bytes) {
        void* p = ws + off;
        off += (bytes + 255) & ~(size_t)255;
        return p;
    };
    int*   counts  = (int*)alloc((size_t)N * 4);
    int*   offsets = (int*)alloc((size_t)(N + 1) * 4);
    int*   cursor  = (int*)alloc((size_t)N * 4);
    int*   psum    = (int*)alloc((size_t)NB * 4);
    int*   pbase   = (int*)alloc((size_t)NB * 4);
    int2*  sedge   = (int2*)alloc((size_t)E * 8);
    unsigned short* w1t_h = (unsigned short*)alloc(49152 * 2);
    unsigned short* w1t_l = (unsigned short*)alloc(49152 * 2);
    unsigned short* w2t_h = (unsigned short*)alloc(49152 * 2);
    unsigned short* w2t_l = (unsigned short*)alloc(49152 * 2);
    unsigned short* fwt_h = (unsigned short*)alloc(65536 * 2);
    unsigned short* fwt_l = (unsigned short*)alloc(65536 * 2);
    unsigned short* xb    = (unsigned short*)alloc((size_t)N * DIM * 2);
    unsigned short* hbuf[3];
    for (int i = 0; i < 3; i++) hbuf[i] = (unsigned short*)alloc((size_t)N * DIM * 2);
    float* outb = (float*)alloc((size_t)N * DIM * 4);
    (void)ws_size; (void)in_sizes; (void)n_in; (void)out_size;

    hipMemsetAsync(counts, 0, (size_t)N * 4, stream);
    hist_kernel<<<(E + 255) / 256, 256, 0, stream>>>(tgt, counts, E);
    wprep_kernel<<<640, 256, 0, stream>>>(w1, w2, fw, w1t_h, w1t_l, w2t_h, w2t_l, fwt_h, fwt_l);
    xcvt_kernel<<<(N * DIM / 4 + 255) / 256, 256, 0, stream>>>(x, xb, N * DIM);
    scan_partial_kernel<<<NB, 256, 0, stream>>>(counts, psum, N);
    scan_small_kernel<<<1, 64, 0, stream>>>(psum, pbase, offsets, NB, N);
    scan_apply_kernel<<<NB, 256, 0, stream>>>(counts, pbase, offsets, cursor, N);
    scatter_kernel<<<(E + 255) / 256, 256, 0, stream>>>(src, tgt, ea, cursor, sedge, E);

    const int GB = (N + 63) / 64;  // 782
    for (int l = 0; l < NLAYERS; l++) {
        const unsigned short* hin = (l == 0) ? xb : hbuf[l - 1];
        agg_kernel<<<(N + 3) / 4, 256, 0, stream>>>(hin, offsets, sedge,
            lw + l * DIM, lb + l * DIM, eps, l, outb, N);
        mlp_fused<<<GB, 256, 0, stream>>>(
            outb,
            w1t_h + l * 16384, w1t_l + l * 16384, b1 + l * DIM,
            w2t_h + l * 16384, w2t_l + l * 16384, b2 + l * DIM,
            hbuf[l], N);
    }
    final_mfma<<<GB, 256, 0, stream>>>(
        xb, hbuf[0], hbuf[1], hbuf[2], fwt_h, fwt_l, fb, out, N);
}

// Round 8
// 406.892 us; speedup vs baseline: 1.7196x; 1.1519x over previous
//
#include <hip/hip_runtime.h>

#define NN 50000
#define NE 800000
#define DIM 128
#define NLAYERS 3

typedef __attribute__((ext_vector_type(8))) short bf16x8;
typedef __attribute__((ext_vector_type(4))) float f32x4;

__device__ __forceinline__ unsigned short f2bf_hi(float f) {
    unsigned int u = __float_as_uint(f);
    u += 0x7FFF + ((u >> 16) & 1);   // RTNE
    return (unsigned short)(u >> 16);
}
__device__ __forceinline__ float bf2f(unsigned short u) {
    return __uint_as_float(((unsigned int)u) << 16);
}

// ---------------- CSR build ----------------
__global__ void hist_kernel(const int* __restrict__ tgt, int* __restrict__ counts, int E) {
    int e = blockIdx.x * blockDim.x + threadIdx.x;
    if (e < E) atomicAdd(&counts[tgt[e]], 1);
}

__global__ __launch_bounds__(256) void scan_partial_kernel(const int* __restrict__ counts,
                                                           int* __restrict__ psum, int n) {
    __shared__ int ws[4];
    int b = blockIdx.x, t = threadIdx.x;
    int idx = b * 1024 + t * 4;
    int v = 0;
    if (idx < n) {
        int4 c = *(const int4*)(counts + idx);
        v = c.x + c.y + c.z + c.w;
    }
#pragma unroll
    for (int o = 32; o > 0; o >>= 1) v += __shfl_xor(v, o);
    int lane = t & 63, wid = t >> 6;
    if (lane == 0) ws[wid] = v;
    __syncthreads();
    if (t == 0) psum[b] = ws[0] + ws[1] + ws[2] + ws[3];
}

__global__ __launch_bounds__(64) void scan_small_kernel(const int* __restrict__ psum,
                                                        int* __restrict__ pbase,
                                                        int* __restrict__ offsets,
                                                        int nb, int n) {
    int lane = threadIdx.x;
    int v = (lane < nb) ? psum[lane] : 0;
    int incl = v;
#pragma unroll
    for (int o = 1; o < 64; o <<= 1) {
        int t = __shfl_up(incl, o);
        if (lane >= o) incl += t;
    }
    if (lane < nb) pbase[lane] = incl - v;
    if (lane == 63) offsets[n] = incl;
}

__global__ __launch_bounds__(256) void scan_apply_kernel(const int* __restrict__ counts,
                                                         const int* __restrict__ pbase,
                                                         int* __restrict__ offsets,
                                                         int* __restrict__ cursor, int n) {
    __shared__ int ws[4];
    int b = blockIdx.x, t = threadIdx.x;
    int lane = t & 63, wid = t >> 6;
    int idx = b * 1024 + t * 4;
    int4 c = make_int4(0, 0, 0, 0);
    if (idx < n) c = *(const int4*)(counts + idx);
    int tsum = c.x + c.y + c.z + c.w;
    int incl = tsum;
#pragma unroll
    for (int o = 1; o < 64; o <<= 1) {
        int tt = __shfl_up(incl, o);
        if (lane >= o) incl += tt;
    }
    if (lane == 63) ws[wid] = incl;
    __syncthreads();
    int wbase = pbase[b];
    for (int w = 0; w < wid; w++) wbase += ws[w];
    if (idx < n) {
        int e0 = wbase + incl - tsum;
        int4 o;
        o.x = e0;
        o.y = e0 + c.x;
        o.z = o.y + c.y;
        o.w = o.z + c.z;
        *(int4*)(offsets + idx) = o;
        *(int4*)(cursor + idx) = o;
    }
}

// edge record: x = src row BYTE offset (src*256), y = edge_attr bits
__global__ void scatter_kernel(const int* __restrict__ src, const int* __restrict__ tgt,
                               const float* __restrict__ ea,
                               int* __restrict__ cursor, int2* __restrict__ sedge, int E) {
    int e = blockIdx.x * blockDim.x + threadIdx.x;
    if (e >= E) return;
    int t = tgt[e];
    int pos = atomicAdd(&cursor[t], 1);
    sedge[pos] = make_int2(src[e] << 8, __float_as_int(ea[e]));
}

// ---------------- x -> bf16 convert ----------------
__global__ __launch_bounds__(256) void xcvt_kernel(const float* __restrict__ x,
                                                   unsigned short* __restrict__ xb, int n) {
    int i = (blockIdx.x * 256 + threadIdx.x) * 4;
    if (i >= n) return;
    float4 v = *(const float4*)(x + i);
    ushort4 o;
    o.x = f2bf_hi(v.x); o.y = f2bf_hi(v.y);
    o.z = f2bf_hi(v.z); o.w = f2bf_hi(v.w);
    *(ushort4*)(xb + i) = o;
}

// ---------------- per-layer aggregation (bf16 gather, quarter-wave) ----------------
// wave per node; 4 quarter-waves own interleaved edges; lane = 16B (8 bf16
// dims) of the 256B row. h-pipeline depth 2 (8 gathers in flight / wave),
// edge-record prefetch depth 3 (record ready 2 iters before its h-load).
__global__ __launch_bounds__(256) void agg_kernel(
    const unsigned short* __restrict__ hprev, const int* __restrict__ offs,
    const int2* __restrict__ sedge,
    const float* __restrict__ lw, const float* __restrict__ lb,
    const float* __restrict__ epsp, int layer,
    float* __restrict__ outb, int N) {
    int wv = threadIdx.x >> 6;
    int node = blockIdx.x * 4 + wv;
    if (node >= N) return;
    int lane = threadIdx.x & 63;
    int q = lane >> 4, r = lane & 15;
    int d0 = r * 8;
    float lwv[8], lbv[8];
    *(float4*)&lwv[0] = *(const float4*)(lw + d0);
    *(float4*)&lwv[4] = *(const float4*)(lw + d0 + 4);
    *(float4*)&lbv[0] = *(const float4*)(lb + d0);
    *(float4*)&lbv[4] = *(const float4*)(lb + d0 + 4);
    int s0 = offs[node], s1 = offs[node + 1];
    int cnt = s1 - s0;
    float a[8];
#pragma unroll
    for (int c = 0; c < 8; c++) a[c] = 0.f;

    const char* hbase = (const char*)hprev + r * 16;

    int idx = s0 + q;
    int2 e0 = sedge[min(idx, s1 - 1)];
    int2 e1 = sedge[min(idx + 4, s1 - 1)];
    int2 e2 = sedge[min(idx + 8, s1 - 1)];
    uint4 h0 = *(const uint4*)(hbase + (unsigned)e0.x);
    uint4 h1 = *(const uint4*)(hbase + (unsigned)e1.x);

    for (int it = idx; it < s1; it += 4) {
        uint4 h2 = *(const uint4*)(hbase + (unsigned)e2.x);
        int2 e3 = sedge[min(it + 12, s1 - 1)];
        float wgt = __int_as_float(e0.y);
        unsigned uu[4] = {h0.x, h0.y, h0.z, h0.w};
#pragma unroll
        for (int c = 0; c < 4; c++) {
            float f0 = __uint_as_float(uu[c] << 16);
            float f1 = __uint_as_float(uu[c] & 0xffff0000u);
            a[2 * c]     += fmaxf(f0 + fmaf(wgt, lwv[2 * c], lbv[2 * c]), 0.f);
            a[2 * c + 1] += fmaxf(f1 + fmaf(wgt, lwv[2 * c + 1], lbv[2 * c + 1]), 0.f);
        }
        e0 = e1; e1 = e2; e2 = e3;
        h0 = h1; h1 = h2;
    }

#pragma unroll
    for (int c = 0; c < 8; c++) {
        a[c] += __shfl_xor(a[c], 16);
        a[c] += __shfl_xor(a[c], 32);
    }

    if (q == 0) {
        float inv = 1.f / (float)cnt;
        float ge = 1.f + epsp[layer];
        uint4 hs = *(const uint4*)(hbase + ((unsigned)node << 8));
        unsigned su[4] = {hs.x, hs.y, hs.z, hs.w};
        float o[8];
#pragma unroll
        for (int c = 0; c < 4; c++) {
            float f0 = __uint_as_float(su[c] << 16);
            float f1 = __uint_as_float(su[c] & 0xffff0000u);
            o[2 * c]     = a[2 * c] * inv + ge * f0;
            o[2 * c + 1] = a[2 * c + 1] * inv + ge * f1;
        }
        float* op = outb + (size_t)node * DIM + d0;
        *(float4*)op = *(float4*)&o[0];
        *(float4*)(op + 4) = *(float4*)&o[4];
    }
}

// ---------------- weight prep: fp32 [k][c] -> bf16 hi/lo transposed [c][k] ----------------
__global__ __launch_bounds__(256) void wprep_kernel(
    const float* __restrict__ w1, const float* __restrict__ w2, const float* __restrict__ fw,
    unsigned short* __restrict__ w1t_h, unsigned short* __restrict__ w1t_l,
    unsigned short* __restrict__ w2t_h, unsigned short* __restrict__ w2t_l,
    unsigned short* __restrict__ fwt_h, unsigned short* __restrict__ fwt_l) {
    int gid = blockIdx.x * 256 + threadIdx.x;
    float v; int oidx;
    unsigned short *oh, *ol;
    if (gid < 49152) {                       // w1 [3][128][128]
        int l = gid >> 14, rem = gid & 16383, k = rem >> 7, c = rem & 127;
        v = w1[gid]; oidx = l * 16384 + c * 128 + k; oh = w1t_h; ol = w1t_l;
    } else if (gid < 98304) {                // w2 [3][128][128]
        int g = gid - 49152;
        int l = g >> 14, rem = g & 16383, k = rem >> 7, c = rem & 127;
        v = w2[g]; oidx = l * 16384 + c * 128 + k; oh = w2t_h; ol = w2t_l;
    } else if (gid < 163840) {               // fw [512][128]
        int g = gid - 98304;
        int k = g >> 7, c = g & 127;
        v = fw[g]; oidx = c * 512 + k; oh = fwt_h; ol = fwt_l;
    } else return;
    unsigned short h = f2bf_hi(v);
    float lo = v - bf2f(h);
    oh[oidx] = h;
    ol[oidx] = f2bf_hi(lo);
}

#define AST 40
#define WST 40

// ---------------- fused 2-layer MLP (bf16x3 MFMA), bf16 output ----------------
__global__ __launch_bounds__(256) void mlp_fused(
    const float* __restrict__ in,
    const unsigned short* __restrict__ w1h, const unsigned short* __restrict__ w1l,
    const float* __restrict__ b1,
    const unsigned short* __restrict__ w2h, const unsigned short* __restrict__ w2l,
    const float* __restrict__ b2,
    unsigned short* __restrict__ out, int N) {
    __shared__ float s_h[64][132];
    __shared__ unsigned short s_ah[64 * AST], s_al[64 * AST];
    __shared__ unsigned short s_wh[128 * WST], s_wl[128 * WST];
    int tid = threadIdx.x;
    int n0 = blockIdx.x * 64;
    int lane = tid & 63, w = tid >> 6;
    int q = lane >> 4, lr = lane & 15;
    int wr = w >> 1, wc = w & 1;
    int sar = tid >> 2, sak = (tid & 3) * 8;
    int swc = tid >> 1, sws = (tid & 1) * 16;

    f32x4 acc[2][4];
#pragma unroll
    for (int i = 0; i < 2; i++)
#pragma unroll
        for (int j = 0; j < 4; j++) acc[i][j] = (f32x4)(0.f);

    // ---------- phase 1: in @ w1 ----------
    for (int k0 = 0; k0 < 128; k0 += 32) {
        float f[8] = {0.f, 0.f, 0.f, 0.f, 0.f, 0.f, 0.f, 0.f};
        if (n0 + sar < NN) {
            const float* ap = in + (size_t)(n0 + sar) * 128 + k0 + sak;
            float4 v0 = *(const float4*)ap;
            float4 v1 = *(const float4*)(ap + 4);
            f[0] = v0.x; f[1] = v0.y; f[2] = v0.z; f[3] = v0.w;
            f[4] = v1.x; f[5] = v1.y; f[6] = v1.z; f[7] = v1.w;
        }
        unsigned int uh[4], ul[4];
#pragma unroll
        for (int i = 0; i < 4; i++) {
            unsigned short h0 = f2bf_hi(f[2 * i]);
            unsigned short h1 = f2bf_hi(f[2 * i + 1]);
            unsigned short l0 = f2bf_hi(f[2 * i] - bf2f(h0));
            unsigned short l1 = f2bf_hi(f[2 * i + 1] - bf2f(h1));
            uh[i] = (unsigned int)h0 | ((unsigned int)h1 << 16);
            ul[i] = (unsigned int)l0 | ((unsigned int)l1 << 16);
        }
        *(uint4*)&s_ah[sar * AST + sak] = make_uint4(uh[0], uh[1], uh[2], uh[3]);
        *(uint4*)&s_al[sar * AST + sak] = make_uint4(ul[0], ul[1], ul[2], ul[3]);
        {
            const unsigned short* wph = w1h + (size_t)swc * 128 + k0 + sws;
            const unsigned short* wpl = w1l + (size_t)swc * 128 + k0 + sws;
            uint4 h0 = *(const uint4*)wph;
            uint4 h1 = *(const uint4*)(wph + 8);
            uint4 l0 = *(const uint4*)wpl;
            uint4 l1 = *(const uint4*)(wpl + 8);
            *(uint4*)&s_wh[swc * WST + sws] = h0;
            *(uint4*)&s_wh[swc * WST + sws + 8] = h1;
            *(uint4*)&s_wl[swc * WST + sws] = l0;
            *(uint4*)&s_wl[swc * WST + sws + 8] = l1;
        }
        __syncthreads();
        bf16x8 ah[2], al_[2], bh[4], bl[4];
#pragma unroll
        for (int i = 0; i < 2; i++) {
            int row = wr * 32 + i * 16 + lr;
            ah[i]  = *(const bf16x8*)&s_ah[row * AST + q * 8];
            al_[i] = *(const bf16x8*)&s_al[row * AST + q * 8];
        }
#pragma unroll
        for (int j = 0; j < 4; j++) {
            int col = wc * 64 + j * 16 + lr;
            bh[j] = *(const bf16x8*)&s_wh[col * WST + q * 8];
            bl[j] = *(const bf16x8*)&s_wl[col * WST + q * 8];
        }
#pragma unroll
        for (int i = 0; i < 2; i++)
#pragma unroll
            for (int j = 0; j < 4; j++) {
                acc[i][j] = __builtin_amdgcn_mfma_f32_16x16x32_bf16(ah[i], bh[j], acc[i][j], 0, 0, 0);
                acc[i][j] = __builtin_amdgcn_mfma_f32_16x16x32_bf16(ah[i], bl[j], acc[i][j], 0, 0, 0);
                acc[i][j] = __builtin_amdgcn_mfma_f32_16x16x32_bf16(al_[i], bh[j], acc[i][j], 0, 0, 0);
            }
        __syncthreads();
    }
    // hidden -> LDS (relu + b1)
#pragma unroll
    for (int i = 0; i < 2; i++) {
        int rbase = wr * 32 + i * 16 + q * 4;
#pragma unroll
        for (int j = 0; j < 4; j++) {
            int col = wc * 64 + j * 16 + lr;
            float bv = b1[col];
#pragma unroll
            for (int r = 0; r < 4; r++)
                s_h[rbase + r][col] = fmaxf(acc[i][j][r] + bv, 0.f);
        }
    }
    __syncthreads();

    // ---------- phase 2: hidden @ w2 ----------
#pragma unroll
    for (int i = 0; i < 2; i++)
#pragma unroll
        for (int j = 0; j < 4; j++) acc[i][j] = (f32x4)(0.f);

    for (int k0 = 0; k0 < 128; k0 += 32) {
        float f[8];
        *(float4*)&f[0] = *(const float4*)&s_h[sar][k0 + sak];
        *(float4*)&f[4] = *(const float4*)&s_h[sar][k0 + sak + 4];
        unsigned int uh[4], ul[4];
#pragma unroll
        for (int i = 0; i < 4; i++) {
            unsigned short h0 = f2bf_hi(f[2 * i]);
            unsigned short h1 = f2bf_hi(f[2 * i + 1]);
            unsigned short l0 = f2bf_hi(f[2 * i] - bf2f(h0));
            unsigned short l1 = f2bf_hi(f[2 * i + 1] - bf2f(h1));
            uh[i] = (unsigned int)h0 | ((unsigned int)h1 << 16);
            ul[i] = (unsigned int)l0 | ((unsigned int)l1 << 16);
        }
        __syncthreads();   // prior MFMA reads of s_ah done before overwrite
        *(uint4*)&s_ah[sar * AST + sak] = make_uint4(uh[0], uh[1], uh[2], uh[3]);
        *(uint4*)&s_al[sar * AST + sak] = make_uint4(ul[0], ul[1], ul[2], ul[3]);
        {
            const unsigned short* wph = w2h + (size_t)swc * 128 + k0 + sws;
            const unsigned short* wpl = w2l + (size_t)swc * 128 + k0 + sws;
            uint4 h0 = *(const uint4*)wph;
            uint4 h1 = *(const uint4*)(wph + 8);
            uint4 l0 = *(const uint4*)wpl;
            uint4 l1 = *(const uint4*)(wpl + 8);
            *(uint4*)&s_wh[swc * WST + sws] = h0;
            *(uint4*)&s_wh[swc * WST + sws + 8] = h1;
            *(uint4*)&s_wl[swc * WST + sws] = l0;
            *(uint4*)&s_wl[swc * WST + sws + 8] = l1;
        }
        __syncthreads();
        bf16x8 ah[2], al_[2], bh[4], bl[4];
#pragma unroll
        for (int i = 0; i < 2; i++) {
            int row = wr * 32 + i * 16 + lr;
            ah[i]  = *(const bf16x8*)&s_ah[row * AST + q * 8];
            al_[i] = *(const bf16x8*)&s_al[row * AST + q * 8];
        }
#pragma unroll
        for (int j = 0; j < 4; j++) {
            int col = wc * 64 + j * 16 + lr;
            bh[j] = *(const bf16x8*)&s_wh[col * WST + q * 8];
            bl[j] = *(const bf16x8*)&s_wl[col * WST + q * 8];
        }
#pragma unroll
        for (int i = 0; i < 2; i++)
#pragma unroll
            for (int j = 0; j < 4; j++) {
                acc[i][j] = __builtin_amdgcn_mfma_f32_16x16x32_bf16(ah[i], bh[j], acc[i][j], 0, 0, 0);
                acc[i][j] = __builtin_amdgcn_mfma_f32_16x16x32_bf16(ah[i], bl[j], acc[i][j], 0, 0, 0);
                acc[i][j] = __builtin_amdgcn_mfma_f32_16x16x32_bf16(al_[i], bh[j], acc[i][j], 0, 0, 0);
            }
    }

#pragma unroll
    for (int i = 0; i < 2; i++) {
        int rbase = wr * 32 + i * 16 + q * 4;
#pragma unroll
        for (int j = 0; j < 4; j++) {
            int col = wc * 64 + j * 16 + lr;
            float bv = b2[col];
#pragma unroll
            for (int r = 0; r < 4; r++) {
                int node = n0 + rbase + r;
                if (node < NN)
                    out[(size_t)node * 128 + col] = f2bf_hi(acc[i][j][r] + bv);
            }
        }
    }
}

// ---------------- final projection: 4 bf16 sources, B hi/lo ----------------
__global__ __launch_bounds__(256) void final_mfma(
    const unsigned short* __restrict__ a0, const unsigned short* __restrict__ a1,
    const unsigned short* __restrict__ a2, const unsigned short* __restrict__ a3,
    const unsigned short* __restrict__ wt_h, const unsigned short* __restrict__ wt_l,
    const float* __restrict__ bias, float* __restrict__ out, int N) {
    __shared__ unsigned short s_ah[64 * AST];
    __shared__ unsigned short s_wh[128 * WST], s_wl[128 * WST];
    const unsigned short* srcs[4] = {a0, a1, a2, a3};
    const int K = 512;
    int tid = threadIdx.x;
    int n0 = blockIdx.x * 64;
    int lane = tid & 63, w = tid >> 6;
    int q = lane >> 4, lr = lane & 15;
    int wr = w >> 1, wc = w & 1;

    f32x4 acc[2][4];
#pragma unroll
    for (int i = 0; i < 2; i++)
#pragma unroll
        for (int j = 0; j < 4; j++) acc[i][j] = (f32x4)(0.f);

    int sar = tid >> 2;
    int sak = (tid & 3) * 8;
    int swc = tid >> 1;
    int sws = (tid & 1) * 16;

    for (int k0 = 0; k0 < K; k0 += 32) {
        const unsigned short* asrc = srcs[k0 >> 7];
        int kl = k0 & 127;
        uint4 av = make_uint4(0, 0, 0, 0);
        if (n0 + sar < N)
            av = *(const uint4*)(asrc + (size_t)(n0 + sar) * 128 + kl + sak);
        *(uint4*)&s_ah[sar * AST + sak] = av;
        {
            const unsigned short* wph = wt_h + (size_t)swc * K + k0 + sws;
            const unsigned short* wpl = wt_l + (size_t)swc * K + k0 + sws;
            uint4 h0 = *(const uint4*)wph;
            uint4 h1 = *(const uint4*)(wph + 8);
            uint4 l0 = *(const uint4*)wpl;
            uint4 l1 = *(const uint4*)(wpl + 8);
            *(uint4*)&s_wh[swc * WST + sws] = h0;
            *(uint4*)&s_wh[swc * WST + sws + 8] = h1;
            *(uint4*)&s_wl[swc * WST + sws] = l0;
            *(uint4*)&s_wl[swc * WST + sws + 8] = l1;
        }
        __syncthreads();
        bf16x8 ah[2], bh[4], bl[4];
#pragma unroll
        for (int i = 0; i < 2; i++) {
            int row = wr * 32 + i * 16 + lr;
            ah[i] = *(const bf16x8*)&s_ah[row * AST + q * 8];
        }
#pragma unroll
        for (int j = 0; j < 4; j++) {
            int col = wc * 64 + j * 16 + lr;
            bh[j] = *(const bf16x8*)&s_wh[col * WST + q * 8];
            bl[j] = *(const bf16x8*)&s_wl[col * WST + q * 8];
        }
#pragma unroll
        for (int i = 0; i < 2; i++)
#pragma unroll
            for (int j = 0; j < 4; j++) {
                acc[i][j] = __builtin_amdgcn_mfma_f32_16x16x32_bf16(ah[i], bh[j], acc[i][j], 0, 0, 0);
                acc[i][j] = __builtin_amdgcn_mfma_f32_16x16x32_bf16(ah[i], bl[j], acc[i][j], 0, 0, 0);
            }
        __syncthreads();
    }

#pragma unroll
    for (int i = 0; i < 2; i++) {
        int rbase = wr * 32 + i * 16 + q * 4;
#pragma unroll
        for (int j = 0; j < 4; j++) {
            int col = wc * 64 + j * 16 + lr;
            float bv = bias[col];
#pragma unroll
            for (int r = 0; r < 4; r++) {
                int node = n0 + rbase + r;
                if (node < N)
                    out[(size_t)node * 128 + col] = acc[i][j][r] + bv;
            }
        }
    }
}

extern "C" void kernel_launch(void* const* d_in, const int* in_sizes, int n_in,
                              void* d_out, int out_size, void* d_ws, size_t ws_size,
                              hipStream_t stream) {
    const float* x   = (const float*)d_in[0];
    const int* edge_index = (const int*)d_in[1];
    const float* ea  = (const float*)d_in[2];
    const float* lw  = (const float*)d_in[3];
    const float* lb  = (const float*)d_in[4];
    const float* eps = (const float*)d_in[5];
    const float* w1  = (const float*)d_in[6];
    const float* b1  = (const float*)d_in[7];
    const float* w2  = (const float*)d_in[8];
    const float* b2  = (const float*)d_in[9];
    const float* fw  = (const float*)d_in[10];
    const float* fb  = (const float*)d_in[11];
    float* out = (float*)d_out;

    const int N = NN, E = NE;
    const int* src = edge_index;
    const int* tgt = edge_index + E;
    const int NB = (N + 1023) / 1024;  // 49

    char* ws = (char*)d_ws;
    size_t off = 0;
    auto alloc = [&](size_t bytes) {
        void* p = ws + off;
        off += (bytes + 255) & ~(size_t)255;
        return p;
    };
    int*   counts  = (int*)alloc((size_t)N * 4);
    int*   offsets = (int*)alloc((size_t)(N + 1) * 4);
    int*   cursor  = (int*)alloc((size_t)N * 4);
    int*   psum    = (int*)alloc((size_t)NB * 4);
    int*   pbase   = (int*)alloc((size_t)NB * 4);
    int2*  sedge   = (int2*)alloc((size_t)E * 8);
    unsigned short* w1t_h = (unsigned short*)alloc(49152 * 2);
    unsigned short* w1t_l = (unsigned short*)alloc(49152 * 2);
    unsigned short* w2t_h = (unsigned short*)alloc(49152 * 2);
    unsigned short* w2t_l = (unsigned short*)alloc(49152 * 2);
    unsigned short* fwt_h = (unsigned short*)alloc(65536 * 2);
    unsigned short* fwt_l = (unsigned short*)alloc(65536 * 2);
    unsigned short* xb    = (unsigned short*)alloc((size_t)N * DIM * 2);
    unsigned short* hbuf[3];
    for (int i = 0; i < 3; i++) hbuf[i] = (unsigned short*)alloc((size_t)N * DIM * 2);
    float* outb = (float*)alloc((size_t)N * DIM * 4);
    (void)ws_size; (void)in_sizes; (void)n_in; (void)out_size;

    hipMemsetAsync(counts, 0, (size_t)N * 4, stream);
    hist_kernel<<<(E + 255) / 256, 256, 0, stream>>>(tgt, counts, E);
    wprep_kernel<<<640, 256, 0, stream>>>(w1, w2, fw, w1t_h, w1t_l, w2t_h, w2t_l, fwt_h, fwt_l);
    xcvt_kernel<<<(N * DIM / 4 + 255) / 256, 256, 0, stream>>>(x, xb, N * DIM);
    scan_partial_kernel<<<NB, 256, 0, stream>>>(counts, psum, N);
    scan_small_kernel<<<1, 64, 0, stream>>>(psum, pbase, offsets, NB, N);
    scan_apply_kernel<<<NB, 256, 0, stream>>>(counts, pbase, offsets, cursor, N);
    scatter_kernel<<<(E + 255) / 256, 256, 0, stream>>>(src, tgt, ea, cursor, sedge, E);

    const int GB = (N + 63) / 64;  // 782
    for (int l = 0; l < NLAYERS; l++) {
        const unsigned short* hin = (l == 0) ? xb : hbuf[l - 1];
        agg_kernel<<<(N + 3) / 4, 256, 0, stream>>>(hin, offsets, sedge,
            lw + l * DIM, lb + l * DIM, eps, l, outb, N);
        mlp_fused<<<GB, 256, 0, stream>>>(
            outb,
            w1t_h + l * 16384, w1t_l + l * 16384, b1 + l * DIM,
            w2t_h + l * 16384, w2t_l + l * 16384, b2 + l * DIM,
            hbuf[l], N);
    }
    final_mfma<<<GB, 256, 0, stream>>>(
        xb, hbuf[0], hbuf[1], hbuf[2], fwt_h, fwt_l, fb, out, N);
}

// Round 9
// 380.148 us; speedup vs baseline: 1.8406x; 1.0704x over previous
//
#include <hip/hip_runtime.h>

#define NN 50000
#define NE 800000
#define DIM 128
#define NLAYERS 3

typedef __attribute__((ext_vector_type(8))) short bf16x8;
typedef __attribute__((ext_vector_type(4))) float f32x4;

__device__ __forceinline__ unsigned short f2bf_hi(float f) {
    unsigned int u = __float_as_uint(f);
    u += 0x7FFF + ((u >> 16) & 1);   // RTNE
    return (unsigned short)(u >> 16);
}
__device__ __forceinline__ float bf2f(unsigned short u) {
    return __uint_as_float(((unsigned int)u) << 16);
}

// ---------------- CSR build ----------------
// rank pass: 4 edges/thread, 4 independent returned atomics in flight.
// counts doubles as the histogram for the scan.
__global__ __launch_bounds__(256) void rank_kernel(const int* __restrict__ tgt,
                                                   int* __restrict__ counts,
                                                   int* __restrict__ rank, int E) {
    int base = (blockIdx.x * 256 + threadIdx.x) * 4;
    if (base >= E) return;          // E % 4 == 0
    int4 t = *(const int4*)(tgt + base);
    int4 r;
    r.x = atomicAdd(&counts[t.x], 1);
    r.y = atomicAdd(&counts[t.y], 1);
    r.z = atomicAdd(&counts[t.z], 1);
    r.w = atomicAdd(&counts[t.w], 1);
    *(int4*)(rank + base) = r;
}

__global__ __launch_bounds__(256) void scan_partial_kernel(const int* __restrict__ counts,
                                                           int* __restrict__ psum, int n) {
    __shared__ int ws[4];
    int b = blockIdx.x, t = threadIdx.x;
    int idx = b * 1024 + t * 4;
    int v = 0;
    if (idx < n) {
        int4 c = *(const int4*)(counts + idx);
        v = c.x + c.y + c.z + c.w;
    }
#pragma unroll
    for (int o = 32; o > 0; o >>= 1) v += __shfl_xor(v, o);
    int lane = t & 63, wid = t >> 6;
    if (lane == 0) ws[wid] = v;
    __syncthreads();
    if (t == 0) psum[b] = ws[0] + ws[1] + ws[2] + ws[3];
}

__global__ __launch_bounds__(64) void scan_small_kernel(const int* __restrict__ psum,
                                                        int* __restrict__ pbase,
                                                        int* __restrict__ offsets,
                                                        int nb, int n) {
    int lane = threadIdx.x;
    int v = (lane < nb) ? psum[lane] : 0;
    int incl = v;
#pragma unroll
    for (int o = 1; o < 64; o <<= 1) {
        int t = __shfl_up(incl, o);
        if (lane >= o) incl += t;
    }
    if (lane < nb) pbase[lane] = incl - v;
    if (lane == 63) offsets[n] = incl;
}

__global__ __launch_bounds__(256) void scan_apply_kernel(const int* __restrict__ counts,
                                                         const int* __restrict__ pbase,
                                                         int* __restrict__ offsets, int n) {
    __shared__ int ws[4];
    int b = blockIdx.x, t = threadIdx.x;
    int lane = t & 63, wid = t >> 6;
    int idx = b * 1024 + t * 4;
    int4 c = make_int4(0, 0, 0, 0);
    if (idx < n) c = *(const int4*)(counts + idx);
    int tsum = c.x + c.y + c.z + c.w;
    int incl = tsum;
#pragma unroll
    for (int o = 1; o < 64; o <<= 1) {
        int tt = __shfl_up(incl, o);
        if (lane >= o) incl += tt;
    }
    if (lane == 63) ws[wid] = incl;
    __syncthreads();
    int wbase = pbase[b];
    for (int w = 0; w < wid; w++) wbase += ws[w];
    if (idx < n) {
        int e0 = wbase + incl - tsum;
        int4 o;
        o.x = e0;
        o.y = e0 + c.x;
        o.z = o.y + c.y;
        o.w = o.z + c.z;
        *(int4*)(offsets + idx) = o;
    }
}

// atomic-free scatter: pos = offsets[tgt] + rank. edge record:
// x = src row BYTE offset (src*256), y = edge_attr bits
__global__ __launch_bounds__(256) void scatter2_kernel(
    const int* __restrict__ src, const int* __restrict__ tgt,
    const float* __restrict__ ea, const int* __restrict__ rank,
    const int* __restrict__ offsets, int2* __restrict__ sedge, int E) {
    int base = (blockIdx.x * 256 + threadIdx.x) * 4;
    if (base >= E) return;
    int4 s = *(const int4*)(src + base);
    int4 t = *(const int4*)(tgt + base);
    int4 r = *(const int4*)(rank + base);
    float4 a = *(const float4*)(ea + base);
    sedge[offsets[t.x] + r.x] = make_int2(s.x << 8, __float_as_int(a.x));
    sedge[offsets[t.y] + r.y] = make_int2(s.y << 8, __float_as_int(a.y));
    sedge[offsets[t.z] + r.z] = make_int2(s.z << 8, __float_as_int(a.z));
    sedge[offsets[t.w] + r.w] = make_int2(s.w << 8, __float_as_int(a.w));
}

// ---------------- x -> bf16 convert ----------------
__global__ __launch_bounds__(256) void xcvt_kernel(const float* __restrict__ x,
                                                   unsigned short* __restrict__ xb, int n) {
    int i = (blockIdx.x * 256 + threadIdx.x) * 4;
    if (i >= n) return;
    float4 v = *(const float4*)(x + i);
    ushort4 o;
    o.x = f2bf_hi(v.x); o.y = f2bf_hi(v.y);
    o.z = f2bf_hi(v.z); o.w = f2bf_hi(v.w);
    *(ushort4*)(xb + i) = o;
}

// ---------------- per-layer aggregation (bf16 gather, quarter-wave) ----------------
__global__ __launch_bounds__(256) void agg_kernel(
    const unsigned short* __restrict__ hprev, const int* __restrict__ offs,
    const int2* __restrict__ sedge,
    const float* __restrict__ lw, const float* __restrict__ lb,
    const float* __restrict__ epsp, int layer,
    float* __restrict__ outb, int N) {
    int wv = threadIdx.x >> 6;
    int node = blockIdx.x * 4 + wv;
    if (node >= N) return;
    int lane = threadIdx.x & 63;
    int q = lane >> 4, r = lane & 15;
    int d0 = r * 8;
    float lwv[8], lbv[8];
    *(float4*)&lwv[0] = *(const float4*)(lw + d0);
    *(float4*)&lwv[4] = *(const float4*)(lw + d0 + 4);
    *(float4*)&lbv[0] = *(const float4*)(lb + d0);
    *(float4*)&lbv[4] = *(const float4*)(lb + d0 + 4);
    int s0 = offs[node], s1 = offs[node + 1];
    int cnt = s1 - s0;
    float a[8];
#pragma unroll
    for (int c = 0; c < 8; c++) a[c] = 0.f;

    const char* hbase = (const char*)hprev + r * 16;

    int idx = s0 + q;
    int2 e0 = sedge[min(idx, s1 - 1)];
    int2 e1 = sedge[min(idx + 4, s1 - 1)];
    int2 e2 = sedge[min(idx + 8, s1 - 1)];
    uint4 h0 = *(const uint4*)(hbase + (unsigned)e0.x);
    uint4 h1 = *(const uint4*)(hbase + (unsigned)e1.x);

    for (int it = idx; it < s1; it += 4) {
        uint4 h2 = *(const uint4*)(hbase + (unsigned)e2.x);
        int2 e3 = sedge[min(it + 12, s1 - 1)];
        float wgt = __int_as_float(e0.y);
        unsigned uu[4] = {h0.x, h0.y, h0.z, h0.w};
#pragma unroll
        for (int c = 0; c < 4; c++) {
            float f0 = __uint_as_float(uu[c] << 16);
            float f1 = __uint_as_float(uu[c] & 0xffff0000u);
            a[2 * c]     += fmaxf(f0 + fmaf(wgt, lwv[2 * c], lbv[2 * c]), 0.f);
            a[2 * c + 1] += fmaxf(f1 + fmaf(wgt, lwv[2 * c + 1], lbv[2 * c + 1]), 0.f);
        }
        e0 = e1; e1 = e2; e2 = e3;
        h0 = h1; h1 = h2;
    }

#pragma unroll
    for (int c = 0; c < 8; c++) {
        a[c] += __shfl_xor(a[c], 16);
        a[c] += __shfl_xor(a[c], 32);
    }

    if (q == 0) {
        float inv = 1.f / (float)cnt;
        float ge = 1.f + epsp[layer];
        uint4 hs = *(const uint4*)(hbase + ((unsigned)node << 8));
        unsigned su[4] = {hs.x, hs.y, hs.z, hs.w};
        float o[8];
#pragma unroll
        for (int c = 0; c < 4; c++) {
            float f0 = __uint_as_float(su[c] << 16);
            float f1 = __uint_as_float(su[c] & 0xffff0000u);
            o[2 * c]     = a[2 * c] * inv + ge * f0;
            o[2 * c + 1] = a[2 * c + 1] * inv + ge * f1;
        }
        float* op = outb + (size_t)node * DIM + d0;
        *(float4*)op = *(float4*)&o[0];
        *(float4*)(op + 4) = *(float4*)&o[4];
    }
}

// ---------------- weight prep: fp32 [k][c] -> bf16 hi/lo transposed [c][k] ----------------
__global__ __launch_bounds__(256) void wprep_kernel(
    const float* __restrict__ w1, const float* __restrict__ w2, const float* __restrict__ fw,
    unsigned short* __restrict__ w1t_h, unsigned short* __restrict__ w1t_l,
    unsigned short* __restrict__ w2t_h, unsigned short* __restrict__ w2t_l,
    unsigned short* __restrict__ fwt_h, unsigned short* __restrict__ fwt_l) {
    int gid = blockIdx.x * 256 + threadIdx.x;
    float v; int oidx;
    unsigned short *oh, *ol;
    if (gid < 49152) {                       // w1 [3][128][128]
        int l = gid >> 14, rem = gid & 16383, k = rem >> 7, c = rem & 127;
        v = w1[gid]; oidx = l * 16384 + c * 128 + k; oh = w1t_h; ol = w1t_l;
    } else if (gid < 98304) {                // w2 [3][128][128]
        int g = gid - 49152;
        int l = g >> 14, rem = g & 16383, k = rem >> 7, c = rem & 127;
        v = w2[g]; oidx = l * 16384 + c * 128 + k; oh = w2t_h; ol = w2t_l;
    } else if (gid < 163840) {               // fw [512][128]
        int g = gid - 98304;
        int k = g >> 7, c = g & 127;
        v = fw[g]; oidx = c * 512 + k; oh = fwt_h; ol = fwt_l;
    } else return;
    unsigned short h = f2bf_hi(v);
    float lo = v - bf2f(h);
    oh[oidx] = h;
    ol[oidx] = f2bf_hi(lo);
}

#define AST 40
#define WST 40

// ---------------- fused 2-layer MLP (bf16x3 MFMA), bf16 output ----------------
__global__ __launch_bounds__(256) void mlp_fused(
    const float* __restrict__ in,
    const unsigned short* __restrict__ w1h, const unsigned short* __restrict__ w1l,
    const float* __restrict__ b1,
    const unsigned short* __restrict__ w2h, const unsigned short* __restrict__ w2l,
    const float* __restrict__ b2,
    unsigned short* __restrict__ out, int N) {
    __shared__ float s_h[64][132];
    __shared__ unsigned short s_ah[64 * AST], s_al[64 * AST];
    __shared__ unsigned short s_wh[128 * WST], s_wl[128 * WST];
    int tid = threadIdx.x;
    int n0 = blockIdx.x * 64;
    int lane = tid & 63, w = tid >> 6;
    int q = lane >> 4, lr = lane & 15;
    int wr = w >> 1, wc = w & 1;
    int sar = tid >> 2, sak = (tid & 3) * 8;
    int swc = tid >> 1, sws = (tid & 1) * 16;

    f32x4 acc[2][4];
#pragma unroll
    for (int i = 0; i < 2; i++)
#pragma unroll
        for (int j = 0; j < 4; j++) acc[i][j] = (f32x4)(0.f);

    // ---------- phase 1: in @ w1 ----------
    for (int k0 = 0; k0 < 128; k0 += 32) {
        float f[8] = {0.f, 0.f, 0.f, 0.f, 0.f, 0.f, 0.f, 0.f};
        if (n0 + sar < NN) {
            const float* ap = in + (size_t)(n0 + sar) * 128 + k0 + sak;
            float4 v0 = *(const float4*)ap;
            float4 v1 = *(const float4*)(ap + 4);
            f[0] = v0.x; f[1] = v0.y; f[2] = v0.z; f[3] = v0.w;
            f[4] = v1.x; f[5] = v1.y; f[6] = v1.z; f[7] = v1.w;
        }
        unsigned int uh[4], ul[4];
#pragma unroll
        for (int i = 0; i < 4; i++) {
            unsigned short h0 = f2bf_hi(f[2 * i]);
            unsigned short h1 = f2bf_hi(f[2 * i + 1]);
            unsigned short l0 = f2bf_hi(f[2 * i] - bf2f(h0));
            unsigned short l1 = f2bf_hi(f[2 * i + 1] - bf2f(h1));
            uh[i] = (unsigned int)h0 | ((unsigned int)h1 << 16);
            ul[i] = (unsigned int)l0 | ((unsigned int)l1 << 16);
        }
        *(uint4*)&s_ah[sar * AST + sak] = make_uint4(uh[0], uh[1], uh[2], uh[3]);
        *(uint4*)&s_al[sar * AST + sak] = make_uint4(ul[0], ul[1], ul[2], ul[3]);
        {
            const unsigned short* wph = w1h + (size_t)swc * 128 + k0 + sws;
            const unsigned short* wpl = w1l + (size_t)swc * 128 + k0 + sws;
            uint4 h0 = *(const uint4*)wph;
            uint4 h1 = *(const uint4*)(wph + 8);
            uint4 l0 = *(const uint4*)wpl;
            uint4 l1 = *(const uint4*)(wpl + 8);
            *(uint4*)&s_wh[swc * WST + sws] = h0;
            *(uint4*)&s_wh[swc * WST + sws + 8] = h1;
            *(uint4*)&s_wl[swc * WST + sws] = l0;
            *(uint4*)&s_wl[swc * WST + sws + 8] = l1;
        }
        __syncthreads();
        bf16x8 ah[2], al_[2], bh[4], bl[4];
#pragma unroll
        for (int i = 0; i < 2; i++) {
            int row = wr * 32 + i * 16 + lr;
            ah[i]  = *(const bf16x8*)&s_ah[row * AST + q * 8];
            al_[i] = *(const bf16x8*)&s_al[row * AST + q * 8];
        }
#pragma unroll
        for (int j = 0; j < 4; j++) {
            int col = wc * 64 + j * 16 + lr;
            bh[j] = *(const bf16x8*)&s_wh[col * WST + q * 8];
            bl[j] = *(const bf16x8*)&s_wl[col * WST + q * 8];
        }
#pragma unroll
        for (int i = 0; i < 2; i++)
#pragma unroll
            for (int j = 0; j < 4; j++) {
                acc[i][j] = __builtin_amdgcn_mfma_f32_16x16x32_bf16(ah[i], bh[j], acc[i][j], 0, 0, 0);
                acc[i][j] = __builtin_amdgcn_mfma_f32_16x16x32_bf16(ah[i], bl[j], acc[i][j], 0, 0, 0);
                acc[i][j] = __builtin_amdgcn_mfma_f32_16x16x32_bf16(al_[i], bh[j], acc[i][j], 0, 0, 0);
            }
        __syncthreads();
    }
    // hidden -> LDS (relu + b1)
#pragma unroll
    for (int i = 0; i < 2; i++) {
        int rbase = wr * 32 + i * 16 + q * 4;
#pragma unroll
        for (int j = 0; j < 4; j++) {
            int col = wc * 64 + j * 16 + lr;
            float bv = b1[col];
#pragma unroll
            for (int r = 0; r < 4; r++)
                s_h[rbase + r][col] = fmaxf(acc[i][j][r] + bv, 0.f);
        }
    }
    __syncthreads();

    // ---------- phase 2: hidden @ w2 ----------
#pragma unroll
    for (int i = 0; i < 2; i++)
#pragma unroll
        for (int j = 0; j < 4; j++) acc[i][j] = (f32x4)(0.f);

    for (int k0 = 0; k0 < 128; k0 += 32) {
        float f[8];
        *(float4*)&f[0] = *(const float4*)&s_h[sar][k0 + sak];
        *(float4*)&f[4] = *(const float4*)&s_h[sar][k0 + sak + 4];
        unsigned int uh[4], ul[4];
#pragma unroll
        for (int i = 0; i < 4; i++) {
            unsigned short h0 = f2bf_hi(f[2 * i]);
            unsigned short h1 = f2bf_hi(f[2 * i + 1]);
            unsigned short l0 = f2bf_hi(f[2 * i] - bf2f(h0));
            unsigned short l1 = f2bf_hi(f[2 * i + 1] - bf2f(h1));
            uh[i] = (unsigned int)h0 | ((unsigned int)h1 << 16);
            ul[i] = (unsigned int)l0 | ((unsigned int)l1 << 16);
        }
        __syncthreads();   // prior MFMA reads of s_ah done before overwrite
        *(uint4*)&s_ah[sar * AST + sak] = make_uint4(uh[0], uh[1], uh[2], uh[3]);
        *(uint4*)&s_al[sar * AST + sak] = make_uint4(ul[0], ul[1], ul[2], ul[3]);
        {
            const unsigned short* wph = w2h + (size_t)swc * 128 + k0 + sws;
            const unsigned short* wpl = w2l + (size_t)swc * 128 + k0 + sws;
            uint4 h0 = *(const uint4*)wph;
            uint4 h1 = *(const uint4*)(wph + 8);
            uint4 l0 = *(const uint4*)wpl;
            uint4 l1 = *(const uint4*)(wpl + 8);
            *(uint4*)&s_wh[swc * WST + sws] = h0;
            *(uint4*)&s_wh[swc * WST + sws + 8] = h1;
            *(uint4*)&s_wl[swc * WST + sws] = l0;
            *(uint4*)&s_wl[swc * WST + sws + 8] = l1;
        }
        __syncthreads();
        bf16x8 ah[2], al_[2], bh[4], bl[4];
#pragma unroll
        for (int i = 0; i < 2; i++) {
            int row = wr * 32 + i * 16 + lr;
            ah[i]  = *(const bf16x8*)&s_ah[row * AST + q * 8];
            al_[i] = *(const bf16x8*)&s_al[row * AST + q * 8];
        }
#pragma unroll
        for (int j = 0; j < 4; j++) {
            int col = wc * 64 + j * 16 + lr;
            bh[j] = *(const bf16x8*)&s_wh[col * WST + q * 8];
            bl[j] = *(const bf16x8*)&s_wl[col * WST + q * 8];
        }
#pragma unroll
        for (int i = 0; i < 2; i++)
#pragma unroll
            for (int j = 0; j < 4; j++) {
                acc[i][j] = __builtin_amdgcn_mfma_f32_16x16x32_bf16(ah[i], bh[j], acc[i][j], 0, 0, 0);
                acc[i][j] = __builtin_amdgcn_mfma_f32_16x16x32_bf16(ah[i], bl[j], acc[i][j], 0, 0, 0);
                acc[i][j] = __builtin_amdgcn_mfma_f32_16x16x32_bf16(al_[i], bh[j], acc[i][j], 0, 0, 0);
            }
    }

#pragma unroll
    for (int i = 0; i < 2; i++) {
        int rbase = wr * 32 + i * 16 + q * 4;
#pragma unroll
        for (int j = 0; j < 4; j++) {
            int col = wc * 64 + j * 16 + lr;
            float bv = b2[col];
#pragma unroll
            for (int r = 0; r < 4; r++) {
                int node = n0 + rbase + r;
                if (node < NN)
                    out[(size_t)node * 128 + col] = f2bf_hi(acc[i][j][r] + bv);
            }
        }
    }
}

// ---------------- final projection: 4 bf16 sources, B hi/lo ----------------
__global__ __launch_bounds__(256) void final_mfma(
    const unsigned short* __restrict__ a0, const unsigned short* __restrict__ a1,
    const unsigned short* __restrict__ a2, const unsigned short* __restrict__ a3,
    const unsigned short* __restrict__ wt_h, const unsigned short* __restrict__ wt_l,
    const float* __restrict__ bias, float* __restrict__ out, int N) {
    __shared__ unsigned short s_ah[64 * AST];
    __shared__ unsigned short s_wh[128 * WST], s_wl[128 * WST];
    const unsigned short* srcs[4] = {a0, a1, a2, a3};
    const int K = 512;
    int tid = threadIdx.x;
    int n0 = blockIdx.x * 64;
    int lane = tid & 63, w = tid >> 6;
    int q = lane >> 4, lr = lane & 15;
    int wr = w >> 1, wc = w & 1;

    f32x4 acc[2][4];
#pragma unroll
    for (int i = 0; i < 2; i++)
#pragma unroll
        for (int j = 0; j < 4; j++) acc[i][j] = (f32x4)(0.f);

    int sar = tid >> 2;
    int sak = (tid & 3) * 8;
    int swc = tid >> 1;
    int sws = (tid & 1) * 16;

    for (int k0 = 0; k0 < K; k0 += 32) {
        const unsigned short* asrc = srcs[k0 >> 7];
        int kl = k0 & 127;
        uint4 av = make_uint4(0, 0, 0, 0);
        if (n0 + sar < N)
            av = *(const uint4*)(asrc + (size_t)(n0 + sar) * 128 + kl + sak);
        *(uint4*)&s_ah[sar * AST + sak] = av;
        {
            const unsigned short* wph = wt_h + (size_t)swc * K + k0 + sws;
            const unsigned short* wpl = wt_l + (size_t)swc * K + k0 + sws;
            uint4 h0 = *(const uint4*)wph;
            uint4 h1 = *(const uint4*)(wph + 8);
            uint4 l0 = *(const uint4*)wpl;
            uint4 l1 = *(const uint4*)(wpl + 8);
            *(uint4*)&s_wh[swc * WST + sws] = h0;
            *(uint4*)&s_wh[swc * WST + sws + 8] = h1;
            *(uint4*)&s_wl[swc * WST + sws] = l0;
            *(uint4*)&s_wl[swc * WST + sws + 8] = l1;
        }
        __syncthreads();
        bf16x8 ah[2], bh[4], bl[4];
#pragma unroll
        for (int i = 0; i < 2; i++) {
            int row = wr * 32 + i * 16 + lr;
            ah[i] = *(const bf16x8*)&s_ah[row * AST + q * 8];
        }
#pragma unroll
        for (int j = 0; j < 4; j++) {
            int col = wc * 64 + j * 16 + lr;
            bh[j] = *(const bf16x8*)&s_wh[col * WST + q * 8];
            bl[j] = *(const bf16x8*)&s_wl[col * WST + q * 8];
        }
#pragma unroll
        for (int i = 0; i < 2; i++)
#pragma unroll
            for (int j = 0; j < 4; j++) {
                acc[i][j] = __builtin_amdgcn_mfma_f32_16x16x32_bf16(ah[i], bh[j], acc[i][j], 0, 0, 0);
                acc[i][j] = __builtin_amdgcn_mfma_f32_16x16x32_bf16(ah[i], bl[j], acc[i][j], 0, 0, 0);
            }
        __syncthreads();
    }

#pragma unroll
    for (int i = 0; i < 2; i++) {
        int rbase = wr * 32 + i * 16 + q * 4;
#pragma unroll
        for (int j = 0; j < 4; j++) {
            int col = wc * 64 + j * 16 + lr;
            float bv = bias[col];
#pragma unroll
            for (int r = 0; r < 4; r++) {
                int node = n0 + rbase + r;
                if (node < N)
                    out[(size_t)node * 128 + col] = acc[i][j][r] + bv;
            }
        }
    }
}

extern "C" void kernel_launch(void* const* d_in, const int* in_sizes, int n_in,
                              void* d_out, int out_size, void* d_ws, size_t ws_size,
                              hipStream_t stream) {
    const float* x   = (const float*)d_in[0];
    const int* edge_index = (const int*)d_in[1];
    const float* ea  = (const float*)d_in[2];
    const float* lw  = (const float*)d_in[3];
    const float* lb  = (const float*)d_in[4];
    const float* eps = (const float*)d_in[5];
    const float* w1  = (const float*)d_in[6];
    const float* b1  = (const float*)d_in[7];
    const float* w2  = (const float*)d_in[8];
    const float* b2  = (const float*)d_in[9];
    const float* fw  = (const float*)d_in[10];
    const float* fb  = (const float*)d_in[11];
    float* out = (float*)d_out;

    const int N = NN, E = NE;
    const int* src = edge_index;
    const int* tgt = edge_index + E;
    const int NB = (N + 1023) / 1024;  // 49

    char* ws = (char*)d_ws;
    size_t off = 0;
    auto alloc = [&](size_t bytes) {
        void* p = ws + off;
        off += (bytes + 255) & ~(size_t)255;
        return p;
    };
    int*   counts  = (int*)alloc((size_t)N * 4);
    int*   offsets = (int*)alloc((size_t)(N + 1) * 4);
    int*   rank    = (int*)alloc((size_t)E * 4);
    int*   psum    = (int*)alloc((size_t)NB * 4);
    int*   pbase   = (int*)alloc((size_t)NB * 4);
    int2*  sedge   = (int2*)alloc((size_t)E * 8);
    unsigned short* w1t_h = (unsigned short*)alloc(49152 * 2);
    unsigned short* w1t_l = (unsigned short*)alloc(49152 * 2);
    unsigned short* w2t_h = (unsigned short*)alloc(49152 * 2);
    unsigned short* w2t_l = (unsigned short*)alloc(49152 * 2);
    unsigned short* fwt_h = (unsigned short*)alloc(65536 * 2);
    unsigned short* fwt_l = (unsigned short*)alloc(65536 * 2);
    unsigned short* xb    = (unsigned short*)alloc((size_t)N * DIM * 2);
    unsigned short* hbuf[3];
    for (int i = 0; i < 3; i++) hbuf[i] = (unsigned short*)alloc((size_t)N * DIM * 2);
    float* outb = (float*)alloc((size_t)N * DIM * 4);
    (void)ws_size; (void)in_sizes; (void)n_in; (void)out_size;

    hipMemsetAsync(counts, 0, (size_t)N * 4, stream);
    rank_kernel<<<(E / 4 + 255) / 256, 256, 0, stream>>>(tgt, counts, rank, E);
    wprep_kernel<<<640, 256, 0, stream>>>(w1, w2, fw, w1t_h, w1t_l, w2t_h, w2t_l, fwt_h, fwt_l);
    xcvt_kernel<<<(N * DIM / 4 + 255) / 256, 256, 0, stream>>>(x, xb, N * DIM);
    scan_partial_kernel<<<NB, 256, 0, stream>>>(counts, psum, N);
    scan_small_kernel<<<1, 64, 0, stream>>>(psum, pbase, offsets, NB, N);
    scan_apply_kernel<<<NB, 256, 0, stream>>>(counts, pbase, offsets, N);
    scatter2_kernel<<<(E / 4 + 255) / 256, 256, 0, stream>>>(src, tgt, ea, rank, offsets, sedge, E);

    const int GB = (N + 63) / 64;  // 782
    for (int l = 0; l < NLAYERS; l++) {
        const unsigned short* hin = (l == 0) ? xb : hbuf[l - 1];
        agg_kernel<<<(N + 3) / 4, 256, 0, stream>>>(hin, offsets, sedge,
            lw + l * DIM, lb + l * DIM, eps, l, outb, N);
        mlp_fused<<<GB, 256, 0, stream>>>(
            outb,
            w1t_h + l * 16384, w1t_l + l * 16384, b1 + l * DIM,
            w2t_h + l * 16384, w2t_l + l * 16384, b2 + l * DIM,
            hbuf[l], N);
    }
    final_mfma<<<GB, 256, 0, stream>>>(
        xb, hbuf[0], hbuf[1], hbuf[2], fwt_h, fwt_l, fb, out, N);
}